// Round 5
// baseline (793.325 us; speedup 1.0000x reference)
//
#include <hip/hip_runtime.h>

static constexpr int N_   = 50000;
static constexpr int E_   = 800000;
static constexpr int G_   = 512;
static constexpr int IN_  = 544;
static constexpr float EPS_ = 1e-5f;

// ---------------- workspace byte offsets ----------------
static constexpr size_t OFF_BN1SUM = 0;          // 512 f
static constexpr size_t OFF_BN1SQ  = 2048;       // 512 f
static constexpr size_t OFF_BN2SUM = 4096;       // 48 f
static constexpr size_t OFF_BN2SQ  = 4288;       // 48 f
static constexpr size_t OFF_BN3SUM = 4480;       // 256 f
static constexpr size_t OFF_BN3SQ  = 5504;       // 256 f
static constexpr size_t OFF_COUNT  = 6528;       // N ints
static constexpr size_t OFF_CUR    = 206528;     // N ints
static constexpr size_t ZERO_BYTES = 406528;     // one memset covers all of the above
static constexpr size_t OFF_OFFS   = 406528;     // N ints
static constexpr size_t OFF_PART   = 606592;     // 64 ints
static constexpr size_t OFF_WC2    = 606848;     // 16*512 f (TRANSPOSED: [16][512])
static constexpr size_t OFF_C2     = 639616;     // 16 f
static constexpr size_t OFF_WP2    = 639744;     // 48*64 f
static constexpr size_t OFF_CP     = 652032;     // 64 f
static constexpr size_t OFF_WGT    = 652288;     // 64*256 f
static constexpr size_t OFF_ASRC   = 719872;     // N*4 f
static constexpr size_t OFF_ADST   = 1519872;    // N*4 f
static constexpr size_t OFF_SRCS   = 2319872;    // E ints
static constexpr size_t OFF_Z      = 5519872;    // N*48 f
static constexpr size_t OFF_H      = 15119872;   // N*64 ushort4 (bf16x4) = 25.6 MB
static constexpr size_t OFF_OUTP   = 66319872;   // N*64 ushort4 (bf16) = 25.6 MB

#define DEV static __device__ __forceinline__

DEV float lrelu(float v) { return v > 0.f ? v : 0.2f * v; }
DEV unsigned short f2bf(float f) {
    unsigned u = __float_as_uint(f);
    return (unsigned short)((u + 0x7fffu + ((u >> 16) & 1u)) >> 16);
}

// ---------- 1. bn1 column stats + edge histogram, 2048 blocks ----------
__global__ __launch_bounds__(256) void k_bn1_hist(
        const float* __restrict__ x, float* __restrict__ sum, float* __restrict__ sq,
        const int* __restrict__ ei, int* __restrict__ count) {
    __shared__ float4 ta[256];
    __shared__ float4 tb[256];
    int t = threadIdx.x;
    int cq = t & 127, rsub = t >> 7;     // 128 col-quads x 2 row-subs
    int c4 = cq << 2;
    float4 a = make_float4(0.f, 0.f, 0.f, 0.f);
    float4 b = make_float4(0.f, 0.f, 0.f, 0.f);
    for (int r = blockIdx.x * 2 + rsub; r < N_; r += gridDim.x * 2) {
        float4 v = *(const float4*)(x + (size_t)r * IN_ + c4);
        a.x += v.x; a.y += v.y; a.z += v.z; a.w += v.w;
        b.x += v.x * v.x; b.y += v.y * v.y; b.z += v.z * v.z; b.w += v.w * v.w;
    }
    ta[t] = a; tb[t] = b;
    __syncthreads();
    if (t < 128) {
        float4 sa = ta[t], sb = tb[t];
        float4 xa = ta[128 + t], xb = tb[128 + t];
        sa.x += xa.x; sa.y += xa.y; sa.z += xa.z; sa.w += xa.w;
        sb.x += xb.x; sb.y += xb.y; sb.z += xb.z; sb.w += xb.w;
        int c = t << 2;
        atomicAdd(&sum[c + 0], sa.x); atomicAdd(&sum[c + 1], sa.y);
        atomicAdd(&sum[c + 2], sa.z); atomicAdd(&sum[c + 3], sa.w);
        atomicAdd(&sq[c + 0], sb.x);  atomicAdd(&sq[c + 1], sb.y);
        atomicAdd(&sq[c + 2], sb.z);  atomicAdd(&sq[c + 3], sb.w);
    }
    for (int k = blockIdx.x * 256 + t; k < E_; k += gridDim.x * 256)
        atomicAdd(&count[ei[E_ + k]], 1);
}

// ---------- 2. fold bn1 into Wc (transposed out) + parallel c2 ----------
__global__ __launch_bounds__(512) void k_fold1(
        const float* __restrict__ sum, const float* __restrict__ sq,
        const float* __restrict__ g, const float* __restrict__ b,
        const float* __restrict__ Wc, const float* __restrict__ bc,
        float* __restrict__ Wc2t, float* __restrict__ c2) {
    __shared__ float c2s[16];
    int j = threadIdx.x;                 // block 512
    if (j < 16) c2s[j] = 0.f;
    float mu  = sum[j] / (float)N_;
    float var = sq[j] / (float)N_ - mu * mu;
    float s   = g[j] * rsqrtf(var + EPS_);
    float tj  = b[j] - mu * s;
    __syncthreads();
    for (int i = 0; i < 16; i++) {
        float wv = Wc[i * 512 + j];
        Wc2t[i * 512 + j] = wv * s;      // coalesced
        float p = tj * wv;
        for (int m = 1; m < 64; m <<= 1) p += __shfl_xor(p, m);
        if ((j & 63) == 0) atomicAdd(&c2s[i], p);
    }
    __syncthreads();
    if (j < 16) c2[j] = c2s[j] + bc[j];
}

// ---------- 3. z + layernorm + fused bn2 stats : 2 nodes/thread, 128 nodes/block ----------
static constexpr int WSTRIDE = 516;      // 512+4: bank-shift 4/row -> conflict-free
__global__ __launch_bounds__(512) void k_z(
        const float* __restrict__ x, const float* __restrict__ Wc2tg,
        const float* __restrict__ c2g, const float* __restrict__ lng,
        const float* __restrict__ lnb, float* __restrict__ z,
        float* __restrict__ bn2sum, float* __restrict__ bn2sq) {
    __shared__ float wc2[16 * WSTRIDE];  // 33 KB
    __shared__ float c2s[16];
    __shared__ float bsum[48];
    __shared__ float bsq[48];
    int t = threadIdx.x;
    for (int q = t; q < 8192; q += 512) {
        int row = q >> 9, col = q & 511;
        wc2[row * WSTRIDE + col] = Wc2tg[q];
    }
    if (t < 16) c2s[t] = c2g[t];
    if (t < 48) { bsum[t] = 0.f; bsq[t] = 0.f; }
    __syncthreads();
    int pr = t >> 3, i = t & 7;          // 64 pairs/block, 8 threads/pair
    int n0 = blockIdx.x * 128 + pr * 2;  // grid 391
    int n1 = n0 + 1;
    bool v0 = n0 < N_, v1 = n1 < N_;
    const float4* xr0 = (const float4*)(x + (size_t)(v0 ? n0 : N_ - 1) * IN_);
    const float4* xr1 = (const float4*)(x + (size_t)(v1 ? n1 : N_ - 1) * IN_);
    const float4* w0 = (const float4*)(wc2 + i * WSTRIDE);
    const float4* w1 = (const float4*)(wc2 + (i + 8) * WSTRIDE);
    float a00 = c2s[i], a01 = c2s[i + 8];
    float a10 = a00, a11 = a01;
    for (int u = 0; u < 128; u++) {
        float4 xa = xr0[u], xb = xr1[u];
        float4 p = w0[u], q4 = w1[u];
        a00 += xa.x * p.x + xa.y * p.y + xa.z * p.z + xa.w * p.w;
        a01 += xa.x * q4.x + xa.y * q4.y + xa.z * q4.z + xa.w * q4.w;
        a10 += xb.x * p.x + xb.y * p.y + xb.z * p.z + xb.w * p.w;
        a11 += xb.x * q4.x + xb.y * q4.y + xb.z * q4.z + xb.w * q4.w;
    }
    // layernorm over last 32 cols for both nodes; thread covers cols i+8*jj
    float va[4], vb[4];
    float sm0 = 0.f, sq0 = 0.f, sm1 = 0.f, sq1 = 0.f;
#pragma unroll
    for (int jj = 0; jj < 4; jj++) {
        va[jj] = x[(size_t)(v0 ? n0 : N_ - 1) * IN_ + 512 + i + 8 * jj];
        vb[jj] = x[(size_t)(v1 ? n1 : N_ - 1) * IN_ + 512 + i + 8 * jj];
        sm0 += va[jj]; sq0 += va[jj] * va[jj];
        sm1 += vb[jj]; sq1 += vb[jj] * vb[jj];
    }
    for (int m = 1; m < 8; m <<= 1) {    // 8-lane groups are lane-aligned
        sm0 += __shfl_xor(sm0, m); sq0 += __shfl_xor(sq0, m);
        sm1 += __shfl_xor(sm1, m); sq1 += __shfl_xor(sq1, m);
    }
    float mu0 = sm0 * (1.f / 32.f), rs0 = rsqrtf(sq0 * (1.f / 32.f) - mu0 * mu0 + EPS_);
    float mu1 = sm1 * (1.f / 32.f), rs1 = rsqrtf(sq1 * (1.f / 32.f) - mu1 * mu1 + EPS_);
    float outa[6], outb[6];
    outa[0] = a00; outa[1] = a01; outb[0] = a10; outb[1] = a11;
#pragma unroll
    for (int jj = 0; jj < 4; jj++) {
        int c = i + 8 * jj;
        float gg = lng[c], bb = lnb[c];
        outa[2 + jj] = (va[jj] - mu0) * rs0 * gg + bb;
        outb[2 + jj] = (vb[jj] - mu1) * rs1 * gg + bb;
    }
    int cols[6] = { i, i + 8, 16 + i, 24 + i, 32 + i, 40 + i };
    if (v0) {
#pragma unroll
        for (int k = 0; k < 6; k++) z[n0 * 48 + cols[k]] = outa[k];
    }
    if (v1) {
#pragma unroll
        for (int k = 0; k < 6; k++) z[n1 * 48 + cols[k]] = outb[k];
    }
    // bn2 partial sums
    float s6[6], q6[6];
#pragma unroll
    for (int k = 0; k < 6; k++) {
        float pa = v0 ? outa[k] : 0.f;
        float pb = v1 ? outb[k] : 0.f;
        s6[k] = pa + pb; q6[k] = pa * pa + pb * pb;
    }
#pragma unroll
    for (int m = 8; m < 64; m <<= 1) {
#pragma unroll
        for (int k = 0; k < 6; k++) {
            s6[k] += __shfl_xor(s6[k], m);
            q6[k] += __shfl_xor(q6[k], m);
        }
    }
    if ((t & 63) < 8) {
#pragma unroll
        for (int k = 0; k < 6; k++) {
            atomicAdd(&bsum[cols[k]], s6[k]);
            atomicAdd(&bsq[cols[k]],  q6[k]);
        }
    }
    __syncthreads();
    if (t < 48) {
        atomicAdd(&bn2sum[t], bsum[t]);
        atomicAdd(&bn2sq[t],  bsq[t]);
    }
}

// ---------- 4. fold bn2 into Wp (block 0) + Wg transpose (blocks 1..64) ----------
__global__ __launch_bounds__(256) void k_fold2_wgt(
        const float* __restrict__ sum, const float* __restrict__ sq,
        const float* __restrict__ g, const float* __restrict__ b,
        const float* __restrict__ Wp, const float* __restrict__ bp,
        float* __restrict__ Wp2, float* __restrict__ cp,
        const float* __restrict__ Wg, float* __restrict__ Wgt) {
    __shared__ float t2[48];
    int t = threadIdx.x;
    if (blockIdx.x > 0) {
        int idx = (blockIdx.x - 1) * 256 + t;
        int c = idx >> 6, k = idx & 63;
        Wgt[k * 256 + c] = Wg[idx];
        return;
    }
    if (t < 48) {
        float mu  = sum[t] / (float)N_;
        float var = sq[t] / (float)N_ - mu * mu;
        float s   = g[t] * rsqrtf(var + EPS_);
        t2[t] = b[t] - mu * s;
        for (int k = 0; k < 64; k++) Wp2[t * 64 + k] = Wp[k * 48 + t] * s;
    }
    __syncthreads();
    if (t < 64) {
        float acc = bp[t];
        for (int j = 0; j < 48; j++) acc += t2[j] * Wp[t * 48 + j];
        cp[t] = acc;
    }
}

// ---------- 5. scan phase 1 ----------
__global__ void k_scan1(const int* __restrict__ count, int* __restrict__ offs,
                        int* __restrict__ part) {
    __shared__ int sd[1024];
    int t = threadIdx.x;
    int idx = blockIdx.x * 1024 + t;
    int v = (idx < N_) ? count[idx] : 0;
    sd[t] = v;
    for (int off = 1; off < 1024; off <<= 1) {
        __syncthreads();
        int tmp = (t >= off) ? sd[t - off] : 0;
        __syncthreads();
        sd[t] += tmp;
    }
    if (idx < N_) offs[idx] = sd[t] - v;
    if (t == 1023) part[blockIdx.x] = sd[1023];
}
// ---------- 6. scan phases 2+3 ----------
__global__ void k_scan23(int* __restrict__ offs, const int* __restrict__ part) {
    __shared__ int bs;
    int t = threadIdx.x, b = blockIdx.x;
    if (t < 64) {
        int v = (t < b) ? part[t] : 0;   // b <= 48 < 64
        for (int m = 1; m < 64; m <<= 1) v += __shfl_xor(v, m);
        if (t == 0) bs = v;
    }
    __syncthreads();
    int idx = b * 1024 + t;
    if (idx < N_) offs[idx] += bs;
}

// ---------- 7. scatter edges into dst-CSR ----------
__global__ void k_scatter(const int* __restrict__ ei, const int* __restrict__ offs,
                          int* __restrict__ cur, int* __restrict__ srcsort) {
    int k = blockIdx.x * 256 + threadIdx.x;
    int src = ei[k], dst = ei[E_ + k];
    int pos = offs[dst] + atomicAdd(&cur[dst], 1);
    srcsort[pos] = src;
}

// ---------- 8. z -> z1 (LDS) -> h(bf16) + attention logits : 128 nodes/block ----------
__global__ __launch_bounds__(512) void k_h2(
        const float* __restrict__ z, const float* __restrict__ Wp2g,
        const float* __restrict__ cpg, const float* __restrict__ Wgtg,
        const float* __restrict__ att_s, const float* __restrict__ att_d,
        ushort4* __restrict__ hbf, float* __restrict__ asrc, float* __restrict__ adst) {
    __shared__ __align__(16) float4 wgh[32 * 64];   // 32 KB (z-tile staged here first)
    __shared__ __align__(16) float  z1t[128 * 64];  // 32 KB
    __shared__ __align__(16) float  wp2[48 * 64];   // 12 KB
    __shared__ float  cps[64];
    __shared__ float4 ats[64];
    __shared__ float4 atd[64];
    int t = threadIdx.x;                 // block 512, grid 391
    int base = blockIdx.x * 128;
    {
        const float4* z4 = (const float4*)(z + (size_t)base * 48);
        float4* zt4 = (float4*)wgh;
        for (int q = t; q < 1536; q += 512) zt4[q] = z4[q];
    }
    for (int q = t; q < 3072; q += 512) wp2[q] = Wp2g[q];
    if (t < 64) {
        cps[t] = cpg[t];
        ats[t] = ((const float4*)att_s)[t];
        atd[t] = ((const float4*)att_d)[t];
    }
    __syncthreads();
    int w = t >> 6, l = t & 63;
    // phase 1: z1 = relu(z @ Wp2 + cp); z rows read as wave-uniform float4
    {
        float wpr[48];
#pragma unroll
        for (int j = 0; j < 48; j++) wpr[j] = wp2[j * 64 + l];
        const float* zt = (const float*)wgh;
        for (int p = 0; p < 16; p++) {
            int nd = p * 8 + w;
            float acc = cps[l];
            const float4* zr4 = (const float4*)(zt + nd * 48);
#pragma unroll
            for (int u = 0; u < 12; u++) {
                float4 zv = zr4[u];
                acc += zv.x * wpr[u * 4 + 0] + zv.y * wpr[u * 4 + 1] +
                       zv.z * wpr[u * 4 + 2] + zv.w * wpr[u * 4 + 3];
            }
            z1t[nd * 64 + l] = fmaxf(acc, 0.f);
        }
    }
    // phase 2: h = z1 @ Wg.T ; k in chunks of 4, z1 read as wave-uniform float4
    const float4* wg4 = (const float4*)Wgtg;
    float4 acc[16];
#pragma unroll
    for (int nd = 0; nd < 16; nd++) acc[nd] = make_float4(0.f, 0.f, 0.f, 0.f);
    for (int half = 0; half < 2; half++) {
        __syncthreads();
        for (int q = t; q < 2048; q += 512) wgh[q] = wg4[half * 2048 + q];
        __syncthreads();
        int kbase = half * 32;
        for (int k4 = 0; k4 < 8; k4++) {
            float4 wv0 = wgh[(k4 * 4 + 0) * 64 + l];
            float4 wv1 = wgh[(k4 * 4 + 1) * 64 + l];
            float4 wv2 = wgh[(k4 * 4 + 2) * 64 + l];
            float4 wv3 = wgh[(k4 * 4 + 3) * 64 + l];
#pragma unroll
            for (int nd = 0; nd < 16; nd++) {
                float4 zv = *(const float4*)&z1t[(w * 16 + nd) * 64 + kbase + k4 * 4];
                acc[nd].x += zv.x * wv0.x + zv.y * wv1.x + zv.z * wv2.x + zv.w * wv3.x;
                acc[nd].y += zv.x * wv0.y + zv.y * wv1.y + zv.z * wv2.y + zv.w * wv3.y;
                acc[nd].z += zv.x * wv0.z + zv.y * wv1.z + zv.z * wv2.z + zv.w * wv3.z;
                acc[nd].w += zv.x * wv0.w + zv.y * wv1.w + zv.z * wv2.w + zv.w * wv3.w;
            }
        }
    }
    float4 as4 = ats[l], ad4 = atd[l];
#pragma unroll
    for (int nd = 0; nd < 16; nd++) {
        int node = base + w * 16 + nd;   // wave-uniform
        if (node < N_) {
            ushort4 hv;
            hv.x = f2bf(acc[nd].x); hv.y = f2bf(acc[nd].y);
            hv.z = f2bf(acc[nd].z); hv.w = f2bf(acc[nd].w);
            hbf[(size_t)node * 64 + l] = hv;
            float pa = acc[nd].x * as4.x + acc[nd].y * as4.y +
                       acc[nd].z * as4.z + acc[nd].w * as4.w;
            float pb = acc[nd].x * ad4.x + acc[nd].y * ad4.y +
                       acc[nd].z * ad4.z + acc[nd].w * ad4.w;
            for (int m = 1; m < 16; m <<= 1) {
                pa += __shfl_xor(pa, m);
                pb += __shfl_xor(pb, m);
            }
            if ((l & 15) == 0) {
                asrc[node * 4 + (l >> 4)] = pa;
                adst[node * 4 + (l >> 4)] = pb;
            }
        }
    }
}

// ---------- 9. per-dst softmax aggregation -> outp (bf16) ----------
__global__ __launch_bounds__(256) void k_agg(
        const int* __restrict__ count, const int* __restrict__ offs,
        const int* __restrict__ srcsort, const float* __restrict__ asrc,
        const float* __restrict__ adst, const ushort4* __restrict__ hbf,
        const float* __restrict__ bg, ushort4* __restrict__ outbf) {
    __shared__ int   s_src[4][128];
    __shared__ float s_wf[4][512];
    int w = threadIdx.x >> 6, l = threadIdx.x & 63;
    int dst = blockIdx.x * 4 + w;        // grid 12500 -> exact
    const float4* asrc4 = (const float4*)asrc;
    float4 bgv = ((const float4*)bg)[l];
    int deg = count[dst];
    if (deg == 0) {
        ushort4 o;
        o.x = f2bf(bgv.x); o.y = f2bf(bgv.y); o.z = f2bf(bgv.z); o.w = f2bf(bgv.w);
        outbf[(size_t)dst * 64 + l] = o;
        return;
    }
    int base = offs[dst];
    float4 ad = ((const float4*)adst)[dst];
    const float NEGINF = -__builtin_inff();
    float4 e0 = make_float4(NEGINF, NEGINF, NEGINF, NEGINF);
    float4 e1 = make_float4(NEGINF, NEGINF, NEGINF, NEGINF);
    if (l < deg) {
        int s0 = srcsort[base + l];
        s_src[w][l] = s0;
        float4 a = asrc4[s0];
        e0 = make_float4(lrelu(a.x + ad.x), lrelu(a.y + ad.y),
                         lrelu(a.z + ad.z), lrelu(a.w + ad.w));
    }
    if (l + 64 < deg) {
        int s1 = srcsort[base + l + 64];
        s_src[w][l + 64] = s1;
        float4 a = asrc4[s1];
        e1 = make_float4(lrelu(a.x + ad.x), lrelu(a.y + ad.y),
                         lrelu(a.z + ad.z), lrelu(a.w + ad.w));
    }
    float4 mx = make_float4(fmaxf(e0.x, e1.x), fmaxf(e0.y, e1.y),
                            fmaxf(e0.z, e1.z), fmaxf(e0.w, e1.w));
    for (int j = l + 128; j < deg; j += 64) {
        int s2 = srcsort[base + j];
        float4 a = asrc4[s2];
        mx.x = fmaxf(mx.x, lrelu(a.x + ad.x)); mx.y = fmaxf(mx.y, lrelu(a.y + ad.y));
        mx.z = fmaxf(mx.z, lrelu(a.z + ad.z)); mx.w = fmaxf(mx.w, lrelu(a.w + ad.w));
    }
    for (int m = 1; m < 64; m <<= 1) {
        mx.x = fmaxf(mx.x, __shfl_xor(mx.x, m));
        mx.y = fmaxf(mx.y, __shfl_xor(mx.y, m));
        mx.z = fmaxf(mx.z, __shfl_xor(mx.z, m));
        mx.w = fmaxf(mx.w, __shfl_xor(mx.w, m));
    }
    float4 sv = make_float4(0.f, 0.f, 0.f, 0.f);
    if (l < deg) {
        float4 ex = make_float4(__expf(e0.x - mx.x), __expf(e0.y - mx.y),
                                __expf(e0.z - mx.z), __expf(e0.w - mx.w));
        *(float4*)&s_wf[w][l * 4] = ex;
        sv.x += ex.x; sv.y += ex.y; sv.z += ex.z; sv.w += ex.w;
    }
    if (l + 64 < deg) {
        float4 ex = make_float4(__expf(e1.x - mx.x), __expf(e1.y - mx.y),
                                __expf(e1.z - mx.z), __expf(e1.w - mx.w));
        *(float4*)&s_wf[w][(l + 64) * 4] = ex;
        sv.x += ex.x; sv.y += ex.y; sv.z += ex.z; sv.w += ex.w;
    }
    for (int j = l + 128; j < deg; j += 64) {
        int s2 = srcsort[base + j];
        float4 a = asrc4[s2];
        sv.x += __expf(lrelu(a.x + ad.x) - mx.x);
        sv.y += __expf(lrelu(a.y + ad.y) - mx.y);
        sv.z += __expf(lrelu(a.z + ad.z) - mx.z);
        sv.w += __expf(lrelu(a.w + ad.w) - mx.w);
    }
    for (int m = 1; m < 64; m <<= 1) {
        sv.x += __shfl_xor(sv.x, m); sv.y += __shfl_xor(sv.y, m);
        sv.z += __shfl_xor(sv.z, m); sv.w += __shfl_xor(sv.w, m);
    }
    int hd = l >> 4;
    float mh  = hd == 0 ? mx.x : hd == 1 ? mx.y : hd == 2 ? mx.z : mx.w;
    float sh  = hd == 0 ? sv.x : hd == 1 ? sv.y : hd == 2 ? sv.z : sv.w;
    float adh = hd == 0 ? ad.x : hd == 1 ? ad.y : hd == 2 ? ad.z : ad.w;
    float inv = 1.f / fmaxf(sh, 1e-16f);
    float4 accv = make_float4(0.f, 0.f, 0.f, 0.f);
    const uint2* h2p = (const uint2*)hbf;
    int dcap = deg < 128 ? deg : 128;
#pragma unroll 2
    for (int j = 0; j < dcap; j++) {
        int src = s_src[w][j];
        float wgt = s_wf[w][j * 4 + hd] * inv;
        uint2 u = h2p[(size_t)src * 64 + l];
        accv.x += wgt * __uint_as_float(u.x << 16);
        accv.y += wgt * __uint_as_float(u.x & 0xffff0000u);
        accv.z += wgt * __uint_as_float(u.y << 16);
        accv.w += wgt * __uint_as_float(u.y & 0xffff0000u);
    }
    for (int j = 128; j < deg; j++) {
        int src = srcsort[base + j];
        float4 a = asrc4[src];
        float ah = hd == 0 ? a.x : hd == 1 ? a.y : hd == 2 ? a.z : a.w;
        float wgt = __expf(lrelu(ah + adh) - mh) * inv;
        uint2 u = h2p[(size_t)src * 64 + l];
        accv.x += wgt * __uint_as_float(u.x << 16);
        accv.y += wgt * __uint_as_float(u.x & 0xffff0000u);
        accv.z += wgt * __uint_as_float(u.y << 16);
        accv.w += wgt * __uint_as_float(u.y & 0xffff0000u);
    }
    ushort4 o;
    o.x = f2bf(accv.x + bgv.x); o.y = f2bf(accv.y + bgv.y);
    o.z = f2bf(accv.z + bgv.z); o.w = f2bf(accv.w + bgv.w);
    outbf[(size_t)dst * 64 + l] = o;
}

// ---------- 10. column stats of outp (bf16, 256 cols), 1024 blocks ----------
__global__ __launch_bounds__(256) void k_bn3_stats(
        const uint2* __restrict__ op2, float* __restrict__ sum, float* __restrict__ sq) {
    __shared__ float4 ta[256];
    __shared__ float4 tb[256];
    int t = threadIdx.x;
    int cq = t & 63, rsub = t >> 6;
    float4 a = make_float4(0.f, 0.f, 0.f, 0.f);
    float4 b = make_float4(0.f, 0.f, 0.f, 0.f);
    for (int r = blockIdx.x * 4 + rsub; r < N_; r += gridDim.x * 4) {
        uint2 u = op2[(size_t)r * 64 + cq];
        float x0 = __uint_as_float(u.x << 16);
        float x1 = __uint_as_float(u.x & 0xffff0000u);
        float x2 = __uint_as_float(u.y << 16);
        float x3 = __uint_as_float(u.y & 0xffff0000u);
        a.x += x0; a.y += x1; a.z += x2; a.w += x3;
        b.x += x0 * x0; b.y += x1 * x1; b.z += x2 * x2; b.w += x3 * x3;
    }
    ta[t] = a; tb[t] = b;
    __syncthreads();
    if (t < 64) {
        float4 sa = ta[t], sb = tb[t];
#pragma unroll
        for (int r = 1; r < 4; r++) {
            float4 xa = ta[r * 64 + t], xb = tb[r * 64 + t];
            sa.x += xa.x; sa.y += xa.y; sa.z += xa.z; sa.w += xa.w;
            sb.x += xb.x; sb.y += xb.y; sb.z += xb.z; sb.w += xb.w;
        }
        int c = t << 2;
        atomicAdd(&sum[c + 0], sa.x); atomicAdd(&sum[c + 1], sa.y);
        atomicAdd(&sum[c + 2], sa.z); atomicAdd(&sum[c + 3], sa.w);
        atomicAdd(&sq[c + 0], sb.x);  atomicAdd(&sq[c + 1], sb.y);
        atomicAdd(&sq[c + 2], sb.z);  atomicAdd(&sq[c + 3], sb.w);
    }
}

// ---------- 11. graph mean-pool of elu(bn3(outp)) + final MLP ----------
__global__ __launch_bounds__(256) void k_pool_mlp(
        const uint2* __restrict__ op2, const int* __restrict__ batch,
        const float* __restrict__ bn3sum, const float* __restrict__ bn3sq,
        const float* __restrict__ bn3g, const float* __restrict__ bn3b,
        const float* __restrict__ W1, const float* __restrict__ b1,
        const float* __restrict__ W2, const float* __restrict__ b2,
        float* __restrict__ out) {
    __shared__ float4 tile[256];
    __shared__ float  pl[256];
    __shared__ float  hm[64];
    int g = blockIdx.x;                  // grid 512
    int t = threadIdx.x;
    int cq = t & 63, rsub = t >> 6;
    int c4 = cq << 2;
    int lo = 0, hi = N_;
    while (lo < hi) { int mid = (lo + hi) >> 1; if (batch[mid] < g) lo = mid + 1; else hi = mid; }
    int start = lo;
    hi = N_;
    while (lo < hi) { int mid = (lo + hi) >> 1; if (batch[mid] < g + 1) lo = mid + 1; else hi = mid; }
    int end = lo;
    float scv[4], shv[4];
#pragma unroll
    for (int k = 0; k < 4; k++) {
        int c = c4 + k;
        float mu  = bn3sum[c] / (float)N_;
        float var = bn3sq[c] / (float)N_ - mu * mu;
        float s   = bn3g[c] * rsqrtf(var + EPS_);
        scv[k] = s; shv[k] = bn3b[c] - mu * s;
    }
    float4 acc = make_float4(0.f, 0.f, 0.f, 0.f);
    for (int n = start + rsub; n < end; n += 4) {
        uint2 u = op2[(size_t)n * 64 + cq];
        float e0 = __uint_as_float(u.x << 16)          * scv[0] + shv[0];
        float e1 = __uint_as_float(u.x & 0xffff0000u)  * scv[1] + shv[1];
        float e2 = __uint_as_float(u.y << 16)          * scv[2] + shv[2];
        float e3 = __uint_as_float(u.y & 0xffff0000u)  * scv[3] + shv[3];
        acc.x += (e0 > 0.f) ? e0 : expm1f(e0);
        acc.y += (e1 > 0.f) ? e1 : expm1f(e1);
        acc.z += (e2 > 0.f) ? e2 : expm1f(e2);
        acc.w += (e3 > 0.f) ? e3 : expm1f(e3);
    }
    tile[t] = acc;
    __syncthreads();
    if (t < 64) {
        float4 s = tile[t];
#pragma unroll
        for (int r = 1; r < 4; r++) {
            float4 xv = tile[r * 64 + t];
            s.x += xv.x; s.y += xv.y; s.z += xv.z; s.w += xv.w;
        }
        float icn = 1.f / fmaxf((float)(end - start), 1.f);
        ((float4*)pl)[t] = make_float4(s.x * icn, s.y * icn, s.z * icn, s.w * icn);
    }
    __syncthreads();
    {
        int j = t >> 2, part = t & 3;
        const float* w1r = W1 + j * 256 + part * 64;
        const float* plr = pl + part * 64;
        float a = 0.f;
#pragma unroll
        for (int c = 0; c < 64; c++) a += w1r[c] * plr[c];
        a += __shfl_xor(a, 1);
        a += __shfl_xor(a, 2);
        if (part == 0) hm[j] = fmaxf(a + b1[j], 0.f);
    }
    __syncthreads();
    if (t < 128) {
        int j = t >> 6, k = t & 63;
        float p = W2[j * 64 + k] * hm[k];
        for (int m = 1; m < 64; m <<= 1) p += __shfl_xor(p, m);
        if (k == 0) out[g * 2 + j] = p + b2[j];
    }
}

extern "C" void kernel_launch(void* const* d_in, const int* in_sizes, int n_in,
                              void* d_out, int out_size, void* d_ws, size_t ws_size,
                              hipStream_t stream) {
    const float* x    = (const float*)d_in[0];
    const int*   ei   = (const int*)d_in[1];
    const int*   batch= (const int*)d_in[2];
    const float* lng  = (const float*)d_in[3];
    const float* lnb  = (const float*)d_in[4];
    const float* bn1g = (const float*)d_in[5];
    const float* bn1b = (const float*)d_in[6];
    const float* Wc   = (const float*)d_in[7];
    const float* bc   = (const float*)d_in[8];
    const float* bn2g = (const float*)d_in[9];
    const float* bn2b = (const float*)d_in[10];
    const float* Wp   = (const float*)d_in[11];
    const float* bp   = (const float*)d_in[12];
    const float* Wg   = (const float*)d_in[13];
    const float* atts = (const float*)d_in[14];
    const float* attd = (const float*)d_in[15];
    const float* bg   = (const float*)d_in[16];
    const float* bn3g = (const float*)d_in[17];
    const float* bn3b = (const float*)d_in[18];
    const float* W1   = (const float*)d_in[19];
    const float* b1   = (const float*)d_in[20];
    const float* W2   = (const float*)d_in[21];
    const float* b2   = (const float*)d_in[22];
    float* out = (float*)d_out;

    char* w8 = (char*)d_ws;
    float* bn1sum = (float*)(w8 + OFF_BN1SUM);
    float* bn1sq  = (float*)(w8 + OFF_BN1SQ);
    float* bn2sum = (float*)(w8 + OFF_BN2SUM);
    float* bn2sq  = (float*)(w8 + OFF_BN2SQ);
    float* bn3sum = (float*)(w8 + OFF_BN3SUM);
    float* bn3sq  = (float*)(w8 + OFF_BN3SQ);
    int*   count  = (int*)(w8 + OFF_COUNT);
    int*   cur    = (int*)(w8 + OFF_CUR);
    int*   offs   = (int*)(w8 + OFF_OFFS);
    int*   part   = (int*)(w8 + OFF_PART);
    float* Wc2t   = (float*)(w8 + OFF_WC2);
    float* c2     = (float*)(w8 + OFF_C2);
    float* Wp2    = (float*)(w8 + OFF_WP2);
    float* cp     = (float*)(w8 + OFF_CP);
    float* Wgt    = (float*)(w8 + OFF_WGT);
    float* asrc   = (float*)(w8 + OFF_ASRC);
    float* adst   = (float*)(w8 + OFF_ADST);
    int*   srcs   = (int*)(w8 + OFF_SRCS);
    float* z      = (float*)(w8 + OFF_Z);
    ushort4* hbf  = (ushort4*)(w8 + OFF_H);
    ushort4* outp = (ushort4*)(w8 + OFF_OUTP);

    hipMemsetAsync(d_ws, 0, ZERO_BYTES, stream);

    k_bn1_hist<<<2048, 256, 0, stream>>>(x, bn1sum, bn1sq, ei, count);
    k_fold1<<<1, 512, 0, stream>>>(bn1sum, bn1sq, bn1g, bn1b, Wc, bc, Wc2t, c2);
    k_z<<<(N_ + 127) / 128, 512, 0, stream>>>(x, Wc2t, c2, lng, lnb, z, bn2sum, bn2sq);
    const int SCANB = (N_ + 1023) / 1024;
    k_scan1<<<SCANB, 1024, 0, stream>>>(count, offs, part);
    k_scan23<<<SCANB, 1024, 0, stream>>>(offs, part);
    k_fold2_wgt<<<65, 256, 0, stream>>>(bn2sum, bn2sq, bn2g, bn2b, Wp, bp, Wp2, cp, Wg, Wgt);
    k_scatter<<<E_ / 256, 256, 0, stream>>>(ei, offs, cur, srcs);
    k_h2<<<(N_ + 127) / 128, 512, 0, stream>>>(z, Wp2, cp, Wgt, atts, attd, hbf, asrc, adst);
    k_agg<<<N_ / 4, 256, 0, stream>>>(count, offs, srcs, asrc, adst, hbf, bg, outp);
    k_bn3_stats<<<1024, 256, 0, stream>>>((const uint2*)outp, bn3sum, bn3sq);
    k_pool_mlp<<<G_, 256, 0, stream>>>((const uint2*)outp, batch, bn3sum, bn3sq,
                                       bn3g, bn3b, W1, b1, W2, b2, out);
}

// Round 6
// 551.165 us; speedup vs baseline: 1.4394x; 1.4394x over previous
//
#include <hip/hip_runtime.h>

static constexpr int N_   = 50000;
static constexpr int E_   = 800000;
static constexpr int G_   = 512;
static constexpr int IN_  = 544;
static constexpr float EPS_ = 1e-5f;

// ---------------- workspace byte offsets ----------------
// Multi-copy accumulators (atomic-contention fix):
static constexpr int BN1C = 32;                  // copies of bn1 stats
static constexpr int BN3C = 16;                  // copies of bn3 stats
static constexpr int BN2C = 8;                   // copies of bn2 stats
static constexpr size_t OFF_BN1C   = 0;          // 32 x 1024 f (sum[512]|sq[512])
static constexpr size_t OFF_BN2C   = 131072;     // 8 x 96 f (sum[48]|sq[48])
static constexpr size_t OFF_BN3C   = 134144;     // 16 x 512 f (sum[256]|sq[256])
static constexpr size_t OFF_COUNT  = 166912;     // N ints
static constexpr size_t OFF_CUR    = 366912;     // N ints
static constexpr size_t ZERO_BYTES = 566912;     // one memset covers all of the above
static constexpr size_t OFF_OFFS   = 566912;     // N ints
static constexpr size_t OFF_WC2    = 766912;     // 16*512 f (TRANSPOSED)
static constexpr size_t OFF_C2     = 799680;     // 16 f
static constexpr size_t OFF_WP2    = 799744;     // 48*64 f
static constexpr size_t OFF_CP     = 812032;     // 64 f
static constexpr size_t OFF_WGT    = 812288;     // 64*256 f
static constexpr size_t OFF_PART   = 877824;     // 64 ints
static constexpr size_t OFF_ASRC   = 878080;     // N*4 f
static constexpr size_t OFF_ADST   = 1678080;    // N*4 f
static constexpr size_t OFF_SRCS   = 2478080;    // E ints
static constexpr size_t OFF_Z      = 5678080;    // N*48 f
static constexpr size_t OFF_H      = 15278080;   // N*64 ushort4 (bf16) = 25.6 MB
static constexpr size_t OFF_OUTP   = 40878080;   // N*64 ushort4 (bf16) = 25.6 MB

#define DEV static __device__ __forceinline__

DEV float lrelu(float v) { return v > 0.f ? v : 0.2f * v; }
DEV unsigned short f2bf(float f) {
    unsigned u = __float_as_uint(f);
    return (unsigned short)((u + 0x7fffu + ((u >> 16) & 1u)) >> 16);
}

// ---------- 1. bn1 column stats (multi-copy) + edge histogram, 2048 blocks ----------
__global__ __launch_bounds__(256) void k_bn1_hist(
        const float* __restrict__ x, float* __restrict__ bn1c,
        const int* __restrict__ ei, int* __restrict__ count) {
    __shared__ float4 ta[256];
    __shared__ float4 tb[256];
    int t = threadIdx.x;
    int cq = t & 127, rsub = t >> 7;     // 128 col-quads x 2 row-subs
    int c4 = cq << 2;
    float4 a = make_float4(0.f, 0.f, 0.f, 0.f);
    float4 b = make_float4(0.f, 0.f, 0.f, 0.f);
    for (int r = blockIdx.x * 2 + rsub; r < N_; r += gridDim.x * 2) {
        float4 v = *(const float4*)(x + (size_t)r * IN_ + c4);
        a.x += v.x; a.y += v.y; a.z += v.z; a.w += v.w;
        b.x += v.x * v.x; b.y += v.y * v.y; b.z += v.z * v.z; b.w += v.w * v.w;
    }
    ta[t] = a; tb[t] = b;
    __syncthreads();
    if (t < 128) {
        float4 sa = ta[t], sb = tb[t];
        float4 xa = ta[128 + t], xb = tb[128 + t];
        sa.x += xa.x; sa.y += xa.y; sa.z += xa.z; sa.w += xa.w;
        sb.x += xb.x; sb.y += xb.y; sb.z += xb.z; sb.w += xb.w;
        float* dst = bn1c + (size_t)(blockIdx.x & (BN1C - 1)) * 1024;
        int c = t << 2;
        atomicAdd(&dst[c + 0], sa.x); atomicAdd(&dst[c + 1], sa.y);
        atomicAdd(&dst[c + 2], sa.z); atomicAdd(&dst[c + 3], sa.w);
        atomicAdd(&dst[512 + c + 0], sb.x); atomicAdd(&dst[512 + c + 1], sb.y);
        atomicAdd(&dst[512 + c + 2], sb.z); atomicAdd(&dst[512 + c + 3], sb.w);
    }
    for (int k = blockIdx.x * 256 + t; k < E_; k += gridDim.x * 256)
        atomicAdd(&count[ei[E_ + k]], 1);
}

// ---------- 2. fold bn1 into Wc (transposed out) + parallel c2 ----------
__global__ __launch_bounds__(512) void k_fold1(
        const float* __restrict__ bn1c,
        const float* __restrict__ g, const float* __restrict__ b,
        const float* __restrict__ Wc, const float* __restrict__ bc,
        float* __restrict__ Wc2t, float* __restrict__ c2) {
    __shared__ float c2s[16];
    int j = threadIdx.x;                 // block 512
    if (j < 16) c2s[j] = 0.f;
    float sum = 0.f, sq = 0.f;
    for (int c = 0; c < BN1C; c++) {     // coalesced across j
        sum += bn1c[c * 1024 + j];
        sq  += bn1c[c * 1024 + 512 + j];
    }
    float mu  = sum / (float)N_;
    float var = sq / (float)N_ - mu * mu;
    float s   = g[j] * rsqrtf(var + EPS_);
    float tj  = b[j] - mu * s;
    __syncthreads();
    for (int i = 0; i < 16; i++) {
        float wv = Wc[i * 512 + j];
        Wc2t[i * 512 + j] = wv * s;      // coalesced
        float p = tj * wv;
        for (int m = 1; m < 64; m <<= 1) p += __shfl_xor(p, m);
        if ((j & 63) == 0) atomicAdd(&c2s[i], p);
    }
    __syncthreads();
    if (j < 16) c2[j] = c2s[j] + bc[j];
}

// ---------- 3. z + layernorm + fused bn2 stats (multi-copy) ----------
static constexpr int WSTRIDE = 516;      // 512+4: bank-shift 4/row -> conflict-free
__global__ __launch_bounds__(512) void k_z(
        const float* __restrict__ x, const float* __restrict__ Wc2tg,
        const float* __restrict__ c2g, const float* __restrict__ lng,
        const float* __restrict__ lnb, float* __restrict__ z,
        float* __restrict__ bn2c) {
    __shared__ float wc2[16 * WSTRIDE];  // 33 KB
    __shared__ float c2s[16];
    __shared__ float bsum[48];
    __shared__ float bsq[48];
    int t = threadIdx.x;
    for (int q = t; q < 8192; q += 512) {
        int row = q >> 9, col = q & 511;
        wc2[row * WSTRIDE + col] = Wc2tg[q];
    }
    if (t < 16) c2s[t] = c2g[t];
    if (t < 48) { bsum[t] = 0.f; bsq[t] = 0.f; }
    __syncthreads();
    int pr = t >> 3, i = t & 7;          // 64 pairs/block, 8 threads/pair
    int n0 = blockIdx.x * 128 + pr * 2;  // grid 391
    int n1 = n0 + 1;
    bool v0 = n0 < N_, v1 = n1 < N_;
    const float4* xr0 = (const float4*)(x + (size_t)(v0 ? n0 : N_ - 1) * IN_);
    const float4* xr1 = (const float4*)(x + (size_t)(v1 ? n1 : N_ - 1) * IN_);
    const float4* w0 = (const float4*)(wc2 + i * WSTRIDE);
    const float4* w1 = (const float4*)(wc2 + (i + 8) * WSTRIDE);
    float a00 = c2s[i], a01 = c2s[i + 8];
    float a10 = a00, a11 = a01;
    for (int u = 0; u < 128; u++) {
        float4 xa = xr0[u], xb = xr1[u];
        float4 p = w0[u], q4 = w1[u];
        a00 += xa.x * p.x + xa.y * p.y + xa.z * p.z + xa.w * p.w;
        a01 += xa.x * q4.x + xa.y * q4.y + xa.z * q4.z + xa.w * q4.w;
        a10 += xb.x * p.x + xb.y * p.y + xb.z * p.z + xb.w * p.w;
        a11 += xb.x * q4.x + xb.y * q4.y + xb.z * q4.z + xb.w * q4.w;
    }
    float va[4], vb[4];
    float sm0 = 0.f, sq0 = 0.f, sm1 = 0.f, sq1 = 0.f;
#pragma unroll
    for (int jj = 0; jj < 4; jj++) {
        va[jj] = x[(size_t)(v0 ? n0 : N_ - 1) * IN_ + 512 + i + 8 * jj];
        vb[jj] = x[(size_t)(v1 ? n1 : N_ - 1) * IN_ + 512 + i + 8 * jj];
        sm0 += va[jj]; sq0 += va[jj] * va[jj];
        sm1 += vb[jj]; sq1 += vb[jj] * vb[jj];
    }
    for (int m = 1; m < 8; m <<= 1) {
        sm0 += __shfl_xor(sm0, m); sq0 += __shfl_xor(sq0, m);
        sm1 += __shfl_xor(sm1, m); sq1 += __shfl_xor(sq1, m);
    }
    float mu0 = sm0 * (1.f / 32.f), rs0 = rsqrtf(sq0 * (1.f / 32.f) - mu0 * mu0 + EPS_);
    float mu1 = sm1 * (1.f / 32.f), rs1 = rsqrtf(sq1 * (1.f / 32.f) - mu1 * mu1 + EPS_);
    float outa[6], outb[6];
    outa[0] = a00; outa[1] = a01; outb[0] = a10; outb[1] = a11;
#pragma unroll
    for (int jj = 0; jj < 4; jj++) {
        int c = i + 8 * jj;
        float gg = lng[c], bb = lnb[c];
        outa[2 + jj] = (va[jj] - mu0) * rs0 * gg + bb;
        outb[2 + jj] = (vb[jj] - mu1) * rs1 * gg + bb;
    }
    int cols[6] = { i, i + 8, 16 + i, 24 + i, 32 + i, 40 + i };
    if (v0) {
#pragma unroll
        for (int k = 0; k < 6; k++) z[n0 * 48 + cols[k]] = outa[k];
    }
    if (v1) {
#pragma unroll
        for (int k = 0; k < 6; k++) z[n1 * 48 + cols[k]] = outb[k];
    }
    float s6[6], q6[6];
#pragma unroll
    for (int k = 0; k < 6; k++) {
        float pa = v0 ? outa[k] : 0.f;
        float pb = v1 ? outb[k] : 0.f;
        s6[k] = pa + pb; q6[k] = pa * pa + pb * pb;
    }
#pragma unroll
    for (int m = 8; m < 64; m <<= 1) {
#pragma unroll
        for (int k = 0; k < 6; k++) {
            s6[k] += __shfl_xor(s6[k], m);
            q6[k] += __shfl_xor(q6[k], m);
        }
    }
    if ((t & 63) < 8) {
#pragma unroll
        for (int k = 0; k < 6; k++) {
            atomicAdd(&bsum[cols[k]], s6[k]);
            atomicAdd(&bsq[cols[k]],  q6[k]);
        }
    }
    __syncthreads();
    if (t < 48) {
        float* dst = bn2c + (size_t)(blockIdx.x & (BN2C - 1)) * 96;
        atomicAdd(&dst[t],      bsum[t]);
        atomicAdd(&dst[48 + t], bsq[t]);
    }
}

// ---------- 4. fold bn2 into Wp (block 0) + Wg transpose (blocks 1..64) ----------
__global__ __launch_bounds__(256) void k_fold2_wgt(
        const float* __restrict__ bn2c,
        const float* __restrict__ g, const float* __restrict__ b,
        const float* __restrict__ Wp, const float* __restrict__ bp,
        float* __restrict__ Wp2, float* __restrict__ cp,
        const float* __restrict__ Wg, float* __restrict__ Wgt) {
    __shared__ float t2[48];
    int t = threadIdx.x;
    if (blockIdx.x > 0) {
        int idx = (blockIdx.x - 1) * 256 + t;
        int c = idx >> 6, k = idx & 63;
        Wgt[k * 256 + c] = Wg[idx];
        return;
    }
    if (t < 48) {
        float sum = 0.f, sq = 0.f;
        for (int c = 0; c < BN2C; c++) {
            sum += bn2c[c * 96 + t];
            sq  += bn2c[c * 96 + 48 + t];
        }
        float mu  = sum / (float)N_;
        float var = sq / (float)N_ - mu * mu;
        float s   = g[t] * rsqrtf(var + EPS_);
        t2[t] = b[t] - mu * s;
        for (int k = 0; k < 64; k++) Wp2[t * 64 + k] = Wp[k * 48 + t] * s;
    }
    __syncthreads();
    if (t < 64) {
        float acc = bp[t];
        for (int j = 0; j < 48; j++) acc += t2[j] * Wp[t * 48 + j];
        cp[t] = acc;
    }
}

// ---------- 5. scan phase 1 ----------
__global__ void k_scan1(const int* __restrict__ count, int* __restrict__ offs,
                        int* __restrict__ part) {
    __shared__ int sd[1024];
    int t = threadIdx.x;
    int idx = blockIdx.x * 1024 + t;
    int v = (idx < N_) ? count[idx] : 0;
    sd[t] = v;
    for (int off = 1; off < 1024; off <<= 1) {
        __syncthreads();
        int tmp = (t >= off) ? sd[t - off] : 0;
        __syncthreads();
        sd[t] += tmp;
    }
    if (idx < N_) offs[idx] = sd[t] - v;
    if (t == 1023) part[blockIdx.x] = sd[1023];
}
// ---------- 6. scan phases 2+3 ----------
__global__ void k_scan23(int* __restrict__ offs, const int* __restrict__ part) {
    __shared__ int bs;
    int t = threadIdx.x, b = blockIdx.x;
    if (t < 64) {
        int v = (t < b) ? part[t] : 0;   // b <= 48 < 64
        for (int m = 1; m < 64; m <<= 1) v += __shfl_xor(v, m);
        if (t == 0) bs = v;
    }
    __syncthreads();
    int idx = b * 1024 + t;
    if (idx < N_) offs[idx] += bs;
}

// ---------- 7. scatter edges into dst-CSR ----------
__global__ void k_scatter(const int* __restrict__ ei, const int* __restrict__ offs,
                          int* __restrict__ cur, int* __restrict__ srcsort) {
    int k = blockIdx.x * 256 + threadIdx.x;
    int src = ei[k], dst = ei[E_ + k];
    int pos = offs[dst] + atomicAdd(&cur[dst], 1);
    srcsort[pos] = src;
}

// ---------- 8. z -> z1 (LDS) -> h(bf16) + attention logits : 128 nodes/block ----------
__global__ __launch_bounds__(512) void k_h2(
        const float* __restrict__ z, const float* __restrict__ Wp2g,
        const float* __restrict__ cpg, const float* __restrict__ Wgtg,
        const float* __restrict__ att_s, const float* __restrict__ att_d,
        ushort4* __restrict__ hbf, float* __restrict__ asrc, float* __restrict__ adst) {
    __shared__ __align__(16) float4 wgh[32 * 64];   // 32 KB (z-tile staged here first)
    __shared__ __align__(16) float  z1t[128 * 64];  // 32 KB
    __shared__ __align__(16) float  wp2[48 * 64];   // 12 KB
    __shared__ float  cps[64];
    __shared__ float4 ats[64];
    __shared__ float4 atd[64];
    int t = threadIdx.x;                 // block 512, grid 391
    int base = blockIdx.x * 128;
    {
        const float4* z4 = (const float4*)(z + (size_t)base * 48);
        float4* zt4 = (float4*)wgh;
        for (int q = t; q < 1536; q += 512) zt4[q] = z4[q];
    }
    for (int q = t; q < 3072; q += 512) wp2[q] = Wp2g[q];
    if (t < 64) {
        cps[t] = cpg[t];
        ats[t] = ((const float4*)att_s)[t];
        atd[t] = ((const float4*)att_d)[t];
    }
    __syncthreads();
    int w = t >> 6, l = t & 63;
    {
        float wpr[48];
#pragma unroll
        for (int j = 0; j < 48; j++) wpr[j] = wp2[j * 64 + l];
        const float* zt = (const float*)wgh;
        for (int p = 0; p < 16; p++) {
            int nd = p * 8 + w;
            float acc = cps[l];
            const float4* zr4 = (const float4*)(zt + nd * 48);
#pragma unroll
            for (int u = 0; u < 12; u++) {
                float4 zv = zr4[u];
                acc += zv.x * wpr[u * 4 + 0] + zv.y * wpr[u * 4 + 1] +
                       zv.z * wpr[u * 4 + 2] + zv.w * wpr[u * 4 + 3];
            }
            z1t[nd * 64 + l] = fmaxf(acc, 0.f);
        }
    }
    const float4* wg4 = (const float4*)Wgtg;
    float4 acc[16];
#pragma unroll
    for (int nd = 0; nd < 16; nd++) acc[nd] = make_float4(0.f, 0.f, 0.f, 0.f);
    for (int half = 0; half < 2; half++) {
        __syncthreads();
        for (int q = t; q < 2048; q += 512) wgh[q] = wg4[half * 2048 + q];
        __syncthreads();
        int kbase = half * 32;
        for (int k4 = 0; k4 < 8; k4++) {
            float4 wv0 = wgh[(k4 * 4 + 0) * 64 + l];
            float4 wv1 = wgh[(k4 * 4 + 1) * 64 + l];
            float4 wv2 = wgh[(k4 * 4 + 2) * 64 + l];
            float4 wv3 = wgh[(k4 * 4 + 3) * 64 + l];
#pragma unroll
            for (int nd = 0; nd < 16; nd++) {
                float4 zv = *(const float4*)&z1t[(w * 16 + nd) * 64 + kbase + k4 * 4];
                acc[nd].x += zv.x * wv0.x + zv.y * wv1.x + zv.z * wv2.x + zv.w * wv3.x;
                acc[nd].y += zv.x * wv0.y + zv.y * wv1.y + zv.z * wv2.y + zv.w * wv3.y;
                acc[nd].z += zv.x * wv0.z + zv.y * wv1.z + zv.z * wv2.z + zv.w * wv3.z;
                acc[nd].w += zv.x * wv0.w + zv.y * wv1.w + zv.z * wv2.w + zv.w * wv3.w;
            }
        }
    }
    float4 as4 = ats[l], ad4 = atd[l];
#pragma unroll
    for (int nd = 0; nd < 16; nd++) {
        int node = base + w * 16 + nd;   // wave-uniform
        if (node < N_) {
            ushort4 hv;
            hv.x = f2bf(acc[nd].x); hv.y = f2bf(acc[nd].y);
            hv.z = f2bf(acc[nd].z); hv.w = f2bf(acc[nd].w);
            hbf[(size_t)node * 64 + l] = hv;
            float pa = acc[nd].x * as4.x + acc[nd].y * as4.y +
                       acc[nd].z * as4.z + acc[nd].w * as4.w;
            float pb = acc[nd].x * ad4.x + acc[nd].y * ad4.y +
                       acc[nd].z * ad4.z + acc[nd].w * ad4.w;
            for (int m = 1; m < 16; m <<= 1) {
                pa += __shfl_xor(pa, m);
                pb += __shfl_xor(pb, m);
            }
            if ((l & 15) == 0) {
                asrc[node * 4 + (l >> 4)] = pa;
                adst[node * 4 + (l >> 4)] = pb;
            }
        }
    }
}

// ---------- 9. per-dst softmax aggregation -> outp (bf16) ----------
__global__ __launch_bounds__(256) void k_agg(
        const int* __restrict__ count, const int* __restrict__ offs,
        const int* __restrict__ srcsort, const float* __restrict__ asrc,
        const float* __restrict__ adst, const ushort4* __restrict__ hbf,
        const float* __restrict__ bg, ushort4* __restrict__ outbf) {
    __shared__ int   s_src[4][128];
    __shared__ float s_wf[4][512];
    int w = threadIdx.x >> 6, l = threadIdx.x & 63;
    int dst = blockIdx.x * 4 + w;        // grid 12500 -> exact
    const float4* asrc4 = (const float4*)asrc;
    float4 bgv = ((const float4*)bg)[l];
    int deg = count[dst];
    if (deg == 0) {
        ushort4 o;
        o.x = f2bf(bgv.x); o.y = f2bf(bgv.y); o.z = f2bf(bgv.z); o.w = f2bf(bgv.w);
        outbf[(size_t)dst * 64 + l] = o;
        return;
    }
    int base = offs[dst];
    float4 ad = ((const float4*)adst)[dst];
    const float NEGINF = -__builtin_inff();
    float4 e0 = make_float4(NEGINF, NEGINF, NEGINF, NEGINF);
    float4 e1 = make_float4(NEGINF, NEGINF, NEGINF, NEGINF);
    if (l < deg) {
        int s0 = srcsort[base + l];
        s_src[w][l] = s0;
        float4 a = asrc4[s0];
        e0 = make_float4(lrelu(a.x + ad.x), lrelu(a.y + ad.y),
                         lrelu(a.z + ad.z), lrelu(a.w + ad.w));
    }
    if (l + 64 < deg) {
        int s1 = srcsort[base + l + 64];
        s_src[w][l + 64] = s1;
        float4 a = asrc4[s1];
        e1 = make_float4(lrelu(a.x + ad.x), lrelu(a.y + ad.y),
                         lrelu(a.z + ad.z), lrelu(a.w + ad.w));
    }
    float4 mx = make_float4(fmaxf(e0.x, e1.x), fmaxf(e0.y, e1.y),
                            fmaxf(e0.z, e1.z), fmaxf(e0.w, e1.w));
    for (int j = l + 128; j < deg; j += 64) {
        int s2 = srcsort[base + j];
        float4 a = asrc4[s2];
        mx.x = fmaxf(mx.x, lrelu(a.x + ad.x)); mx.y = fmaxf(mx.y, lrelu(a.y + ad.y));
        mx.z = fmaxf(mx.z, lrelu(a.z + ad.z)); mx.w = fmaxf(mx.w, lrelu(a.w + ad.w));
    }
    for (int m = 1; m < 64; m <<= 1) {
        mx.x = fmaxf(mx.x, __shfl_xor(mx.x, m));
        mx.y = fmaxf(mx.y, __shfl_xor(mx.y, m));
        mx.z = fmaxf(mx.z, __shfl_xor(mx.z, m));
        mx.w = fmaxf(mx.w, __shfl_xor(mx.w, m));
    }
    float4 sv = make_float4(0.f, 0.f, 0.f, 0.f);
    if (l < deg) {
        float4 ex = make_float4(__expf(e0.x - mx.x), __expf(e0.y - mx.y),
                                __expf(e0.z - mx.z), __expf(e0.w - mx.w));
        *(float4*)&s_wf[w][l * 4] = ex;
        sv.x += ex.x; sv.y += ex.y; sv.z += ex.z; sv.w += ex.w;
    }
    if (l + 64 < deg) {
        float4 ex = make_float4(__expf(e1.x - mx.x), __expf(e1.y - mx.y),
                                __expf(e1.z - mx.z), __expf(e1.w - mx.w));
        *(float4*)&s_wf[w][(l + 64) * 4] = ex;
        sv.x += ex.x; sv.y += ex.y; sv.z += ex.z; sv.w += ex.w;
    }
    for (int j = l + 128; j < deg; j += 64) {
        int s2 = srcsort[base + j];
        float4 a = asrc4[s2];
        sv.x += __expf(lrelu(a.x + ad.x) - mx.x);
        sv.y += __expf(lrelu(a.y + ad.y) - mx.y);
        sv.z += __expf(lrelu(a.z + ad.z) - mx.z);
        sv.w += __expf(lrelu(a.w + ad.w) - mx.w);
    }
    for (int m = 1; m < 64; m <<= 1) {
        sv.x += __shfl_xor(sv.x, m); sv.y += __shfl_xor(sv.y, m);
        sv.z += __shfl_xor(sv.z, m); sv.w += __shfl_xor(sv.w, m);
    }
    int hd = l >> 4;
    float mh  = hd == 0 ? mx.x : hd == 1 ? mx.y : hd == 2 ? mx.z : mx.w;
    float sh  = hd == 0 ? sv.x : hd == 1 ? sv.y : hd == 2 ? sv.z : sv.w;
    float adh = hd == 0 ? ad.x : hd == 1 ? ad.y : hd == 2 ? ad.z : ad.w;
    float inv = 1.f / fmaxf(sh, 1e-16f);
    float4 accv = make_float4(0.f, 0.f, 0.f, 0.f);
    const uint2* h2p = (const uint2*)hbf;
    int dcap = deg < 128 ? deg : 128;
#pragma unroll 2
    for (int j = 0; j < dcap; j++) {
        int src = s_src[w][j];
        float wgt = s_wf[w][j * 4 + hd] * inv;
        uint2 u = h2p[(size_t)src * 64 + l];
        accv.x += wgt * __uint_as_float(u.x << 16);
        accv.y += wgt * __uint_as_float(u.x & 0xffff0000u);
        accv.z += wgt * __uint_as_float(u.y << 16);
        accv.w += wgt * __uint_as_float(u.y & 0xffff0000u);
    }
    for (int j = 128; j < deg; j++) {
        int src = srcsort[base + j];
        float4 a = asrc4[src];
        float ah = hd == 0 ? a.x : hd == 1 ? a.y : hd == 2 ? a.z : a.w;
        float wgt = __expf(lrelu(ah + adh) - mh) * inv;
        uint2 u = h2p[(size_t)src * 64 + l];
        accv.x += wgt * __uint_as_float(u.x << 16);
        accv.y += wgt * __uint_as_float(u.x & 0xffff0000u);
        accv.z += wgt * __uint_as_float(u.y << 16);
        accv.w += wgt * __uint_as_float(u.y & 0xffff0000u);
    }
    ushort4 o;
    o.x = f2bf(accv.x + bgv.x); o.y = f2bf(accv.y + bgv.y);
    o.z = f2bf(accv.z + bgv.z); o.w = f2bf(accv.w + bgv.w);
    outbf[(size_t)dst * 64 + l] = o;
}

// ---------- 10. column stats of outp (bf16, multi-copy), 1024 blocks ----------
__global__ __launch_bounds__(256) void k_bn3_stats(
        const uint2* __restrict__ op2, float* __restrict__ bn3c) {
    __shared__ float4 ta[256];
    __shared__ float4 tb[256];
    int t = threadIdx.x;
    int cq = t & 63, rsub = t >> 6;
    float4 a = make_float4(0.f, 0.f, 0.f, 0.f);
    float4 b = make_float4(0.f, 0.f, 0.f, 0.f);
    for (int r = blockIdx.x * 4 + rsub; r < N_; r += gridDim.x * 4) {
        uint2 u = op2[(size_t)r * 64 + cq];
        float x0 = __uint_as_float(u.x << 16);
        float x1 = __uint_as_float(u.x & 0xffff0000u);
        float x2 = __uint_as_float(u.y << 16);
        float x3 = __uint_as_float(u.y & 0xffff0000u);
        a.x += x0; a.y += x1; a.z += x2; a.w += x3;
        b.x += x0 * x0; b.y += x1 * x1; b.z += x2 * x2; b.w += x3 * x3;
    }
    ta[t] = a; tb[t] = b;
    __syncthreads();
    if (t < 64) {
        float4 sa = ta[t], sb = tb[t];
#pragma unroll
        for (int r = 1; r < 4; r++) {
            float4 xa = ta[r * 64 + t], xb = tb[r * 64 + t];
            sa.x += xa.x; sa.y += xa.y; sa.z += xa.z; sa.w += xa.w;
            sb.x += xb.x; sb.y += xb.y; sb.z += xb.z; sb.w += xb.w;
        }
        float* dst = bn3c + (size_t)(blockIdx.x & (BN3C - 1)) * 512;
        int c = t << 2;
        atomicAdd(&dst[c + 0], sa.x); atomicAdd(&dst[c + 1], sa.y);
        atomicAdd(&dst[c + 2], sa.z); atomicAdd(&dst[c + 3], sa.w);
        atomicAdd(&dst[256 + c + 0], sb.x); atomicAdd(&dst[256 + c + 1], sb.y);
        atomicAdd(&dst[256 + c + 2], sb.z); atomicAdd(&dst[256 + c + 3], sb.w);
    }
}

// ---------- 11. graph mean-pool of elu(bn3(outp)) + final MLP ----------
__global__ __launch_bounds__(256) void k_pool_mlp(
        const uint2* __restrict__ op2, const int* __restrict__ batch,
        const float* __restrict__ bn3c,
        const float* __restrict__ bn3g, const float* __restrict__ bn3b,
        const float* __restrict__ W1, const float* __restrict__ b1,
        const float* __restrict__ W2, const float* __restrict__ b2,
        float* __restrict__ out) {
    __shared__ float4 tile[256];
    __shared__ float  pl[256];
    __shared__ float  hm[64];
    __shared__ float  s3[256];
    __shared__ float  q3[256];
    int g = blockIdx.x;                  // grid 512
    int t = threadIdx.x;
    int cq = t & 63, rsub = t >> 6;
    int c4 = cq << 2;
    {   // collapse bn3 stat copies into LDS
        float s = 0.f, q = 0.f;
        for (int c = 0; c < BN3C; c++) {
            s += bn3c[c * 512 + t];
            q += bn3c[c * 512 + 256 + t];
        }
        s3[t] = s; q3[t] = q;
    }
    int lo = 0, hi = N_;
    while (lo < hi) { int mid = (lo + hi) >> 1; if (batch[mid] < g) lo = mid + 1; else hi = mid; }
    int start = lo;
    hi = N_;
    while (lo < hi) { int mid = (lo + hi) >> 1; if (batch[mid] < g + 1) lo = mid + 1; else hi = mid; }
    int end = lo;
    __syncthreads();
    float scv[4], shv[4];
#pragma unroll
    for (int k = 0; k < 4; k++) {
        int c = c4 + k;
        float mu  = s3[c] / (float)N_;
        float var = q3[c] / (float)N_ - mu * mu;
        float s   = bn3g[c] * rsqrtf(var + EPS_);
        scv[k] = s; shv[k] = bn3b[c] - mu * s;
    }
    float4 acc = make_float4(0.f, 0.f, 0.f, 0.f);
    for (int n = start + rsub; n < end; n += 4) {
        uint2 u = op2[(size_t)n * 64 + cq];
        float e0 = __uint_as_float(u.x << 16)          * scv[0] + shv[0];
        float e1 = __uint_as_float(u.x & 0xffff0000u)  * scv[1] + shv[1];
        float e2 = __uint_as_float(u.y << 16)          * scv[2] + shv[2];
        float e3 = __uint_as_float(u.y & 0xffff0000u)  * scv[3] + shv[3];
        acc.x += (e0 > 0.f) ? e0 : expm1f(e0);
        acc.y += (e1 > 0.f) ? e1 : expm1f(e1);
        acc.z += (e2 > 0.f) ? e2 : expm1f(e2);
        acc.w += (e3 > 0.f) ? e3 : expm1f(e3);
    }
    tile[t] = acc;
    __syncthreads();
    if (t < 64) {
        float4 s = tile[t];
#pragma unroll
        for (int r = 1; r < 4; r++) {
            float4 xv = tile[r * 64 + t];
            s.x += xv.x; s.y += xv.y; s.z += xv.z; s.w += xv.w;
        }
        float icn = 1.f / fmaxf((float)(end - start), 1.f);
        ((float4*)pl)[t] = make_float4(s.x * icn, s.y * icn, s.z * icn, s.w * icn);
    }
    __syncthreads();
    {
        int j = t >> 2, part = t & 3;
        const float* w1r = W1 + j * 256 + part * 64;
        const float* plr = pl + part * 64;
        float a = 0.f;
#pragma unroll
        for (int c = 0; c < 64; c++) a += w1r[c] * plr[c];
        a += __shfl_xor(a, 1);
        a += __shfl_xor(a, 2);
        if (part == 0) hm[j] = fmaxf(a + b1[j], 0.f);
    }
    __syncthreads();
    if (t < 128) {
        int j = t >> 6, k = t & 63;
        float p = W2[j * 64 + k] * hm[k];
        for (int m = 1; m < 64; m <<= 1) p += __shfl_xor(p, m);
        if (k == 0) out[g * 2 + j] = p + b2[j];
    }
}

extern "C" void kernel_launch(void* const* d_in, const int* in_sizes, int n_in,
                              void* d_out, int out_size, void* d_ws, size_t ws_size,
                              hipStream_t stream) {
    const float* x    = (const float*)d_in[0];
    const int*   ei   = (const int*)d_in[1];
    const int*   batch= (const int*)d_in[2];
    const float* lng  = (const float*)d_in[3];
    const float* lnb  = (const float*)d_in[4];
    const float* bn1g = (const float*)d_in[5];
    const float* bn1b = (const float*)d_in[6];
    const float* Wc   = (const float*)d_in[7];
    const float* bc   = (const float*)d_in[8];
    const float* bn2g = (const float*)d_in[9];
    const float* bn2b = (const float*)d_in[10];
    const float* Wp   = (const float*)d_in[11];
    const float* bp   = (const float*)d_in[12];
    const float* Wg   = (const float*)d_in[13];
    const float* atts = (const float*)d_in[14];
    const float* attd = (const float*)d_in[15];
    const float* bg   = (const float*)d_in[16];
    const float* bn3g = (const float*)d_in[17];
    const float* bn3b = (const float*)d_in[18];
    const float* W1   = (const float*)d_in[19];
    const float* b1   = (const float*)d_in[20];
    const float* W2   = (const float*)d_in[21];
    const float* b2   = (const float*)d_in[22];
    float* out = (float*)d_out;

    char* w8 = (char*)d_ws;
    float* bn1c   = (float*)(w8 + OFF_BN1C);
    float* bn2c   = (float*)(w8 + OFF_BN2C);
    float* bn3c   = (float*)(w8 + OFF_BN3C);
    int*   count  = (int*)(w8 + OFF_COUNT);
    int*   cur    = (int*)(w8 + OFF_CUR);
    int*   offs   = (int*)(w8 + OFF_OFFS);
    int*   part   = (int*)(w8 + OFF_PART);
    float* Wc2t   = (float*)(w8 + OFF_WC2);
    float* c2     = (float*)(w8 + OFF_C2);
    float* Wp2    = (float*)(w8 + OFF_WP2);
    float* cp     = (float*)(w8 + OFF_CP);
    float* Wgt    = (float*)(w8 + OFF_WGT);
    float* asrc   = (float*)(w8 + OFF_ASRC);
    float* adst   = (float*)(w8 + OFF_ADST);
    int*   srcs   = (int*)(w8 + OFF_SRCS);
    float* z      = (float*)(w8 + OFF_Z);
    ushort4* hbf  = (ushort4*)(w8 + OFF_H);
    ushort4* outp = (ushort4*)(w8 + OFF_OUTP);

    hipMemsetAsync(d_ws, 0, ZERO_BYTES, stream);

    k_bn1_hist<<<2048, 256, 0, stream>>>(x, bn1c, ei, count);
    k_fold1<<<1, 512, 0, stream>>>(bn1c, bn1g, bn1b, Wc, bc, Wc2t, c2);
    k_z<<<(N_ + 127) / 128, 512, 0, stream>>>(x, Wc2t, c2, lng, lnb, z, bn2c);
    const int SCANB = (N_ + 1023) / 1024;
    k_scan1<<<SCANB, 1024, 0, stream>>>(count, offs, part);
    k_scan23<<<SCANB, 1024, 0, stream>>>(offs, part);
    k_fold2_wgt<<<65, 256, 0, stream>>>(bn2c, bn2g, bn2b, Wp, bp, Wp2, cp, Wg, Wgt);
    k_scatter<<<E_ / 256, 256, 0, stream>>>(ei, offs, cur, srcs);
    k_h2<<<(N_ + 127) / 128, 512, 0, stream>>>(z, Wp2, cp, Wgt, atts, attd, hbf, asrc, adst);
    k_agg<<<N_ / 4, 256, 0, stream>>>(count, offs, srcs, asrc, adst, hbf, bg, outp);
    k_bn3_stats<<<1024, 256, 0, stream>>>((const uint2*)outp, bn3c);
    k_pool_mlp<<<G_, 256, 0, stream>>>((const uint2*)outp, batch, bn3c,
                                       bn3g, bn3b, W1, b1, W2, b2, out);
}

// Round 7
// 519.400 us; speedup vs baseline: 1.5274x; 1.0612x over previous
//
#include <hip/hip_runtime.h>

static constexpr int N_   = 50000;
static constexpr int E_   = 800000;
static constexpr int G_   = 512;
static constexpr int IN_  = 544;
static constexpr float EPS_ = 1e-5f;
static constexpr int NBLK = 782;                 // radix pass-1 blocks (1024 edges each)

// ---------------- workspace byte offsets ----------------
static constexpr int BN1C = 32;
static constexpr int BN3C = 16;
static constexpr int BN2C = 8;
static constexpr size_t OFF_BN1C   = 0;          // 32 x 1024 f
static constexpr size_t OFF_BN2C   = 131072;     // 8 x 96 f
static constexpr size_t OFF_BN3C   = 134144;     // 16 x 512 f
static constexpr size_t ZERO_BYTES = 166912;     // only the bn copies need zeroing
static constexpr size_t OFF_COUNT  = 166912;     // N ints (fully written by k_rsort2)
static constexpr size_t OFF_OFFS   = 366912;     // N ints (fully written by k_rsort2)
static constexpr size_t OFF_BH     = 566912;     // NBLK*256 ints
static constexpr size_t OFF_BTOT   = 1367680;    // 256 ints
static constexpr size_t OFF_BBASE  = 1368704;    // 257 ints (pad)
static constexpr size_t OFF_SORTD  = 1369856;    // E u16
static constexpr size_t OFF_SORTS  = 2969856;    // E ints
static constexpr size_t OFF_SRCS   = 6169856;    // E ints (final CSR srcs)
static constexpr size_t OFF_WC2    = 9369856;    // 16*512 f (transposed)
static constexpr size_t OFF_C2     = 9402624;    // 16 f
static constexpr size_t OFF_WP2    = 9402880;    // 48*64 f
static constexpr size_t OFF_CP     = 9415168;    // 64 f
static constexpr size_t OFF_WGT    = 9415424;    // 64*256 f
static constexpr size_t OFF_ASRC   = 9480960;    // N*4 f
static constexpr size_t OFF_ADST   = 10280960;   // N*4 f
static constexpr size_t OFF_Z      = 11080960;   // N*48 f
static constexpr size_t OFF_H      = 20680960;   // N*64 ushort4 (bf16)
static constexpr size_t OFF_OUTP   = 46280960;   // N*64 ushort4 (bf16); ends ~71.9 MB

#define DEV static __device__ __forceinline__

DEV float lrelu(float v) { return v > 0.f ? v : 0.2f * v; }
DEV unsigned short f2bf(float f) {
    unsigned u = __float_as_uint(f);
    return (unsigned short)((u + 0x7fffu + ((u >> 16) & 1u)) >> 16);
}

// ---------- 1. bn1 column stats (multi-copy), 2048 blocks ----------
__global__ __launch_bounds__(256) void k_bn1(
        const float* __restrict__ x, float* __restrict__ bn1c) {
    __shared__ float4 ta[256];
    __shared__ float4 tb[256];
    int t = threadIdx.x;
    int cq = t & 127, rsub = t >> 7;
    int c4 = cq << 2;
    float4 a = make_float4(0.f, 0.f, 0.f, 0.f);
    float4 b = make_float4(0.f, 0.f, 0.f, 0.f);
    for (int r = blockIdx.x * 2 + rsub; r < N_; r += gridDim.x * 2) {
        float4 v = *(const float4*)(x + (size_t)r * IN_ + c4);
        a.x += v.x; a.y += v.y; a.z += v.z; a.w += v.w;
        b.x += v.x * v.x; b.y += v.y * v.y; b.z += v.z * v.z; b.w += v.w * v.w;
    }
    ta[t] = a; tb[t] = b;
    __syncthreads();
    if (t < 128) {
        float4 sa = ta[t], sb = tb[t];
        float4 xa = ta[128 + t], xb = tb[128 + t];
        sa.x += xa.x; sa.y += xa.y; sa.z += xa.z; sa.w += xa.w;
        sb.x += xb.x; sb.y += xb.y; sb.z += xb.z; sb.w += xb.w;
        float* dst = bn1c + (size_t)(blockIdx.x & (BN1C - 1)) * 1024;
        int c = t << 2;
        atomicAdd(&dst[c + 0], sa.x); atomicAdd(&dst[c + 1], sa.y);
        atomicAdd(&dst[c + 2], sa.z); atomicAdd(&dst[c + 3], sa.w);
        atomicAdd(&dst[512 + c + 0], sb.x); atomicAdd(&dst[512 + c + 1], sb.y);
        atomicAdd(&dst[512 + c + 2], sb.z); atomicAdd(&dst[512 + c + 3], sb.w);
    }
}

// ---------- radix pass A: per-block 256-bucket histogram of dst>>8 ----------
__global__ __launch_bounds__(256) void k_rhist(
        const int* __restrict__ ei, int* __restrict__ blockhist) {
    __shared__ int hist[256];
    int t = threadIdx.x;
    hist[t] = 0;
    __syncthreads();
    int base = blockIdx.x * 1024;
#pragma unroll
    for (int k = 0; k < 4; k++) {
        int i = base + k * 256 + t;
        if (i < E_) atomicAdd(&hist[ei[E_ + i] >> 8], 1);
    }
    __syncthreads();
    blockhist[blockIdx.x * 256 + t] = hist[t];
}

// ---------- radix pass B: per-bucket exclusive scan over blocks ----------
__global__ __launch_bounds__(256) void k_rscan(
        int* __restrict__ blockhist, int* __restrict__ btot) {
    __shared__ int a[256];
    int b = blockIdx.x, t = threadIdx.x;     // grid 256
    int v[4]; int s = 0;
#pragma unroll
    for (int k = 0; k < 4; k++) {
        int j = t * 4 + k;
        v[k] = (j < NBLK) ? blockhist[j * 256 + b] : 0;
        s += v[k];
    }
    a[t] = s;
    for (int off = 1; off < 256; off <<= 1) {
        __syncthreads();
        int tmp = (t >= off) ? a[t - off] : 0;
        __syncthreads();
        a[t] += tmp;
    }
    __syncthreads();
    int run = a[t] - s;                      // exclusive base for this thread's 4 blocks
#pragma unroll
    for (int k = 0; k < 4; k++) {
        int j = t * 4 + k;
        if (j < NBLK) { blockhist[j * 256 + b] = run; run += v[k]; }
    }
    if (t == 255) btot[b] = a[255];
}

// ---------- radix pass C: scan 256 bucket totals ----------
__global__ __launch_bounds__(256) void k_rbase(
        const int* __restrict__ btot, int* __restrict__ bbase) {
    __shared__ int a[256];
    int t = threadIdx.x;
    int v = btot[t];
    a[t] = v;
    for (int off = 1; off < 256; off <<= 1) {
        __syncthreads();
        int tmp = (t >= off) ? a[t - off] : 0;
        __syncthreads();
        a[t] += tmp;
    }
    __syncthreads();
    bbase[t] = a[t] - v;
    if (t == 255) bbase[256] = a[255];
}

// ---------- radix pass D: scatter into buckets (LDS cursors, no global atomics) ----------
__global__ __launch_bounds__(256) void k_rscatter(
        const int* __restrict__ ei, const int* __restrict__ blockhist,
        const int* __restrict__ bbase, unsigned short* __restrict__ sortd,
        int* __restrict__ sorts) {
    __shared__ int cursor[256];
    int t = threadIdx.x;
    cursor[t] = bbase[t] + blockhist[blockIdx.x * 256 + t];
    __syncthreads();
    int base = blockIdx.x * 1024;
#pragma unroll
    for (int k = 0; k < 4; k++) {
        int i = base + k * 256 + t;
        if (i < E_) {
            int d = ei[E_ + i], s = ei[i];
            int pos = atomicAdd(&cursor[d >> 8], 1);
            sortd[pos] = (unsigned short)d;
            sorts[pos] = s;
        }
    }
}

// ---------- radix pass E: in-bucket counting sort by dst&255 -> CSR ----------
__global__ __launch_bounds__(256) void k_rsort2(
        const unsigned short* __restrict__ sortd, const int* __restrict__ sorts,
        const int* __restrict__ bbase, int* __restrict__ count,
        int* __restrict__ offs, int* __restrict__ srcsort) {
    __shared__ int hist[256];
    __shared__ int pref[256];
    __shared__ int cursor[256];
    int b = blockIdx.x, t = threadIdx.x;     // grid 196
    int base = bbase[b], endp = bbase[b + 1];
    hist[t] = 0;
    __syncthreads();
    for (int i = base + t; i < endp; i += 256)
        atomicAdd(&hist[sortd[i] & 255], 1);
    __syncthreads();
    int hv = hist[t];
    pref[t] = hv;
    for (int off = 1; off < 256; off <<= 1) {
        __syncthreads();
        int tmp = (t >= off) ? pref[t - off] : 0;
        __syncthreads();
        pref[t] += tmp;
    }
    __syncthreads();
    int ex = pref[t] - hv;                   // exclusive prefix
    int idx = (b << 8) + t;
    if (idx < N_) { count[idx] = hv; offs[idx] = base + ex; }
    cursor[t] = ex;
    __syncthreads();
    for (int i = base + t; i < endp; i += 256) {
        int d = sortd[i], s = sorts[i];
        int pos = base + atomicAdd(&cursor[d & 255], 1);
        srcsort[pos] = s;
    }
}

// ---------- 2. fold bn1 into Wc (transposed out) + parallel c2 ----------
__global__ __launch_bounds__(512) void k_fold1(
        const float* __restrict__ bn1c,
        const float* __restrict__ g, const float* __restrict__ b,
        const float* __restrict__ Wc, const float* __restrict__ bc,
        float* __restrict__ Wc2t, float* __restrict__ c2) {
    __shared__ float c2s[16];
    int j = threadIdx.x;                 // block 512
    if (j < 16) c2s[j] = 0.f;
    float sum = 0.f, sq = 0.f;
    for (int c = 0; c < BN1C; c++) {
        sum += bn1c[c * 1024 + j];
        sq  += bn1c[c * 1024 + 512 + j];
    }
    float mu  = sum / (float)N_;
    float var = sq / (float)N_ - mu * mu;
    float s   = g[j] * rsqrtf(var + EPS_);
    float tj  = b[j] - mu * s;
    __syncthreads();
    for (int i = 0; i < 16; i++) {
        float wv = Wc[i * 512 + j];
        Wc2t[i * 512 + j] = wv * s;
        float p = tj * wv;
        for (int m = 1; m < 64; m <<= 1) p += __shfl_xor(p, m);
        if ((j & 63) == 0) atomicAdd(&c2s[i], p);
    }
    __syncthreads();
    if (j < 16) c2[j] = c2s[j] + bc[j];
}

// ---------- 3. z + layernorm + fused bn2 stats (multi-copy) ----------
static constexpr int WSTRIDE = 516;
__global__ __launch_bounds__(512) void k_z(
        const float* __restrict__ x, const float* __restrict__ Wc2tg,
        const float* __restrict__ c2g, const float* __restrict__ lng,
        const float* __restrict__ lnb, float* __restrict__ z,
        float* __restrict__ bn2c) {
    __shared__ float wc2[16 * WSTRIDE];
    __shared__ float c2s[16];
    __shared__ float bsum[48];
    __shared__ float bsq[48];
    int t = threadIdx.x;
    for (int q = t; q < 8192; q += 512) {
        int row = q >> 9, col = q & 511;
        wc2[row * WSTRIDE + col] = Wc2tg[q];
    }
    if (t < 16) c2s[t] = c2g[t];
    if (t < 48) { bsum[t] = 0.f; bsq[t] = 0.f; }
    __syncthreads();
    int pr = t >> 3, i = t & 7;
    int n0 = blockIdx.x * 128 + pr * 2;
    int n1 = n0 + 1;
    bool v0 = n0 < N_, v1 = n1 < N_;
    const float4* xr0 = (const float4*)(x + (size_t)(v0 ? n0 : N_ - 1) * IN_);
    const float4* xr1 = (const float4*)(x + (size_t)(v1 ? n1 : N_ - 1) * IN_);
    const float4* w0 = (const float4*)(wc2 + i * WSTRIDE);
    const float4* w1 = (const float4*)(wc2 + (i + 8) * WSTRIDE);
    float a00 = c2s[i], a01 = c2s[i + 8];
    float a10 = a00, a11 = a01;
    for (int u = 0; u < 128; u++) {
        float4 xa = xr0[u], xb = xr1[u];
        float4 p = w0[u], q4 = w1[u];
        a00 += xa.x * p.x + xa.y * p.y + xa.z * p.z + xa.w * p.w;
        a01 += xa.x * q4.x + xa.y * q4.y + xa.z * q4.z + xa.w * q4.w;
        a10 += xb.x * p.x + xb.y * p.y + xb.z * p.z + xb.w * p.w;
        a11 += xb.x * q4.x + xb.y * q4.y + xb.z * q4.z + xb.w * q4.w;
    }
    float va[4], vb[4];
    float sm0 = 0.f, sq0 = 0.f, sm1 = 0.f, sq1 = 0.f;
#pragma unroll
    for (int jj = 0; jj < 4; jj++) {
        va[jj] = x[(size_t)(v0 ? n0 : N_ - 1) * IN_ + 512 + i + 8 * jj];
        vb[jj] = x[(size_t)(v1 ? n1 : N_ - 1) * IN_ + 512 + i + 8 * jj];
        sm0 += va[jj]; sq0 += va[jj] * va[jj];
        sm1 += vb[jj]; sq1 += vb[jj] * vb[jj];
    }
    for (int m = 1; m < 8; m <<= 1) {
        sm0 += __shfl_xor(sm0, m); sq0 += __shfl_xor(sq0, m);
        sm1 += __shfl_xor(sm1, m); sq1 += __shfl_xor(sq1, m);
    }
    float mu0 = sm0 * (1.f / 32.f), rs0 = rsqrtf(sq0 * (1.f / 32.f) - mu0 * mu0 + EPS_);
    float mu1 = sm1 * (1.f / 32.f), rs1 = rsqrtf(sq1 * (1.f / 32.f) - mu1 * mu1 + EPS_);
    float outa[6], outb[6];
    outa[0] = a00; outa[1] = a01; outb[0] = a10; outb[1] = a11;
#pragma unroll
    for (int jj = 0; jj < 4; jj++) {
        int c = i + 8 * jj;
        float gg = lng[c], bb = lnb[c];
        outa[2 + jj] = (va[jj] - mu0) * rs0 * gg + bb;
        outb[2 + jj] = (vb[jj] - mu1) * rs1 * gg + bb;
    }
    int cols[6] = { i, i + 8, 16 + i, 24 + i, 32 + i, 40 + i };
    if (v0) {
#pragma unroll
        for (int k = 0; k < 6; k++) z[n0 * 48 + cols[k]] = outa[k];
    }
    if (v1) {
#pragma unroll
        for (int k = 0; k < 6; k++) z[n1 * 48 + cols[k]] = outb[k];
    }
    float s6[6], q6[6];
#pragma unroll
    for (int k = 0; k < 6; k++) {
        float pa = v0 ? outa[k] : 0.f;
        float pb = v1 ? outb[k] : 0.f;
        s6[k] = pa + pb; q6[k] = pa * pa + pb * pb;
    }
#pragma unroll
    for (int m = 8; m < 64; m <<= 1) {
#pragma unroll
        for (int k = 0; k < 6; k++) {
            s6[k] += __shfl_xor(s6[k], m);
            q6[k] += __shfl_xor(q6[k], m);
        }
    }
    if ((t & 63) < 8) {
#pragma unroll
        for (int k = 0; k < 6; k++) {
            atomicAdd(&bsum[cols[k]], s6[k]);
            atomicAdd(&bsq[cols[k]],  q6[k]);
        }
    }
    __syncthreads();
    if (t < 48) {
        float* dst = bn2c + (size_t)(blockIdx.x & (BN2C - 1)) * 96;
        atomicAdd(&dst[t],      bsum[t]);
        atomicAdd(&dst[48 + t], bsq[t]);
    }
}

// ---------- 4. fold bn2 into Wp (block 0) + Wg transpose (blocks 1..64) ----------
__global__ __launch_bounds__(256) void k_fold2_wgt(
        const float* __restrict__ bn2c,
        const float* __restrict__ g, const float* __restrict__ b,
        const float* __restrict__ Wp, const float* __restrict__ bp,
        float* __restrict__ Wp2, float* __restrict__ cp,
        const float* __restrict__ Wg, float* __restrict__ Wgt) {
    __shared__ float t2[48];
    int t = threadIdx.x;
    if (blockIdx.x > 0) {
        int idx = (blockIdx.x - 1) * 256 + t;
        int c = idx >> 6, k = idx & 63;
        Wgt[k * 256 + c] = Wg[idx];
        return;
    }
    if (t < 48) {
        float sum = 0.f, sq = 0.f;
        for (int c = 0; c < BN2C; c++) {
            sum += bn2c[c * 96 + t];
            sq  += bn2c[c * 96 + 48 + t];
        }
        float mu  = sum / (float)N_;
        float var = sq / (float)N_ - mu * mu;
        float s   = g[t] * rsqrtf(var + EPS_);
        t2[t] = b[t] - mu * s;
        for (int k = 0; k < 64; k++) Wp2[t * 64 + k] = Wp[k * 48 + t] * s;
    }
    __syncthreads();
    if (t < 64) {
        float acc = bp[t];
        for (int j = 0; j < 48; j++) acc += t2[j] * Wp[t * 48 + j];
        cp[t] = acc;
    }
}

// ---------- 8. z -> z1 (LDS) -> h(bf16) + attention logits : 128 nodes/block ----------
__global__ __launch_bounds__(512) void k_h2(
        const float* __restrict__ z, const float* __restrict__ Wp2g,
        const float* __restrict__ cpg, const float* __restrict__ Wgtg,
        const float* __restrict__ att_s, const float* __restrict__ att_d,
        ushort4* __restrict__ hbf, float* __restrict__ asrc, float* __restrict__ adst) {
    __shared__ __align__(16) float4 wgh[32 * 64];
    __shared__ __align__(16) float  z1t[128 * 64];
    __shared__ __align__(16) float  wp2[48 * 64];
    __shared__ float  cps[64];
    __shared__ float4 ats[64];
    __shared__ float4 atd[64];
    int t = threadIdx.x;
    int base = blockIdx.x * 128;
    {
        const float4* z4 = (const float4*)(z + (size_t)base * 48);
        float4* zt4 = (float4*)wgh;
        for (int q = t; q < 1536; q += 512) zt4[q] = z4[q];
    }
    for (int q = t; q < 3072; q += 512) wp2[q] = Wp2g[q];
    if (t < 64) {
        cps[t] = cpg[t];
        ats[t] = ((const float4*)att_s)[t];
        atd[t] = ((const float4*)att_d)[t];
    }
    __syncthreads();
    int w = t >> 6, l = t & 63;
    {
        float wpr[48];
#pragma unroll
        for (int j = 0; j < 48; j++) wpr[j] = wp2[j * 64 + l];
        const float* zt = (const float*)wgh;
        for (int p = 0; p < 16; p++) {
            int nd = p * 8 + w;
            float acc = cps[l];
            const float4* zr4 = (const float4*)(zt + nd * 48);
#pragma unroll
            for (int u = 0; u < 12; u++) {
                float4 zv = zr4[u];
                acc += zv.x * wpr[u * 4 + 0] + zv.y * wpr[u * 4 + 1] +
                       zv.z * wpr[u * 4 + 2] + zv.w * wpr[u * 4 + 3];
            }
            z1t[nd * 64 + l] = fmaxf(acc, 0.f);
        }
    }
    const float4* wg4 = (const float4*)Wgtg;
    float4 acc[16];
#pragma unroll
    for (int nd = 0; nd < 16; nd++) acc[nd] = make_float4(0.f, 0.f, 0.f, 0.f);
    for (int half = 0; half < 2; half++) {
        __syncthreads();
        for (int q = t; q < 2048; q += 512) wgh[q] = wg4[half * 2048 + q];
        __syncthreads();
        int kbase = half * 32;
        for (int k4 = 0; k4 < 8; k4++) {
            float4 wv0 = wgh[(k4 * 4 + 0) * 64 + l];
            float4 wv1 = wgh[(k4 * 4 + 1) * 64 + l];
            float4 wv2 = wgh[(k4 * 4 + 2) * 64 + l];
            float4 wv3 = wgh[(k4 * 4 + 3) * 64 + l];
#pragma unroll
            for (int nd = 0; nd < 16; nd++) {
                float4 zv = *(const float4*)&z1t[(w * 16 + nd) * 64 + kbase + k4 * 4];
                acc[nd].x += zv.x * wv0.x + zv.y * wv1.x + zv.z * wv2.x + zv.w * wv3.x;
                acc[nd].y += zv.x * wv0.y + zv.y * wv1.y + zv.z * wv2.y + zv.w * wv3.y;
                acc[nd].z += zv.x * wv0.z + zv.y * wv1.z + zv.z * wv2.z + zv.w * wv3.z;
                acc[nd].w += zv.x * wv0.w + zv.y * wv1.w + zv.z * wv2.w + zv.w * wv3.w;
            }
        }
    }
    float4 as4 = ats[l], ad4 = atd[l];
#pragma unroll
    for (int nd = 0; nd < 16; nd++) {
        int node = base + w * 16 + nd;
        if (node < N_) {
            ushort4 hv;
            hv.x = f2bf(acc[nd].x); hv.y = f2bf(acc[nd].y);
            hv.z = f2bf(acc[nd].z); hv.w = f2bf(acc[nd].w);
            hbf[(size_t)node * 64 + l] = hv;
            float pa = acc[nd].x * as4.x + acc[nd].y * as4.y +
                       acc[nd].z * as4.z + acc[nd].w * as4.w;
            float pb = acc[nd].x * ad4.x + acc[nd].y * ad4.y +
                       acc[nd].z * ad4.z + acc[nd].w * ad4.w;
            for (int m = 1; m < 16; m <<= 1) {
                pa += __shfl_xor(pa, m);
                pb += __shfl_xor(pb, m);
            }
            if ((l & 15) == 0) {
                asrc[node * 4 + (l >> 4)] = pa;
                adst[node * 4 + (l >> 4)] = pb;
            }
        }
    }
}

// ---------- 9. per-dst softmax aggregation -> outp (bf16) ----------
__global__ __launch_bounds__(256) void k_agg(
        const int* __restrict__ count, const int* __restrict__ offs,
        const int* __restrict__ srcsort, const float* __restrict__ asrc,
        const float* __restrict__ adst, const ushort4* __restrict__ hbf,
        const float* __restrict__ bg, ushort4* __restrict__ outbf) {
    __shared__ int   s_src[4][128];
    __shared__ float s_wf[4][512];
    int w = threadIdx.x >> 6, l = threadIdx.x & 63;
    int dst = blockIdx.x * 4 + w;
    const float4* asrc4 = (const float4*)asrc;
    float4 bgv = ((const float4*)bg)[l];
    int deg = count[dst];
    if (deg == 0) {
        ushort4 o;
        o.x = f2bf(bgv.x); o.y = f2bf(bgv.y); o.z = f2bf(bgv.z); o.w = f2bf(bgv.w);
        outbf[(size_t)dst * 64 + l] = o;
        return;
    }
    int base = offs[dst];
    float4 ad = ((const float4*)adst)[dst];
    const float NEGINF = -__builtin_inff();
    float4 e0 = make_float4(NEGINF, NEGINF, NEGINF, NEGINF);
    float4 e1 = make_float4(NEGINF, NEGINF, NEGINF, NEGINF);
    if (l < deg) {
        int s0 = srcsort[base + l];
        s_src[w][l] = s0;
        float4 a = asrc4[s0];
        e0 = make_float4(lrelu(a.x + ad.x), lrelu(a.y + ad.y),
                         lrelu(a.z + ad.z), lrelu(a.w + ad.w));
    }
    if (l + 64 < deg) {
        int s1 = srcsort[base + l + 64];
        s_src[w][l + 64] = s1;
        float4 a = asrc4[s1];
        e1 = make_float4(lrelu(a.x + ad.x), lrelu(a.y + ad.y),
                         lrelu(a.z + ad.z), lrelu(a.w + ad.w));
    }
    float4 mx = make_float4(fmaxf(e0.x, e1.x), fmaxf(e0.y, e1.y),
                            fmaxf(e0.z, e1.z), fmaxf(e0.w, e1.w));
    for (int j = l + 128; j < deg; j += 64) {
        int s2 = srcsort[base + j];
        float4 a = asrc4[s2];
        mx.x = fmaxf(mx.x, lrelu(a.x + ad.x)); mx.y = fmaxf(mx.y, lrelu(a.y + ad.y));
        mx.z = fmaxf(mx.z, lrelu(a.z + ad.z)); mx.w = fmaxf(mx.w, lrelu(a.w + ad.w));
    }
    for (int m = 1; m < 64; m <<= 1) {
        mx.x = fmaxf(mx.x, __shfl_xor(mx.x, m));
        mx.y = fmaxf(mx.y, __shfl_xor(mx.y, m));
        mx.z = fmaxf(mx.z, __shfl_xor(mx.z, m));
        mx.w = fmaxf(mx.w, __shfl_xor(mx.w, m));
    }
    float4 sv = make_float4(0.f, 0.f, 0.f, 0.f);
    if (l < deg) {
        float4 ex = make_float4(__expf(e0.x - mx.x), __expf(e0.y - mx.y),
                                __expf(e0.z - mx.z), __expf(e0.w - mx.w));
        *(float4*)&s_wf[w][l * 4] = ex;
        sv.x += ex.x; sv.y += ex.y; sv.z += ex.z; sv.w += ex.w;
    }
    if (l + 64 < deg) {
        float4 ex = make_float4(__expf(e1.x - mx.x), __expf(e1.y - mx.y),
                                __expf(e1.z - mx.z), __expf(e1.w - mx.w));
        *(float4*)&s_wf[w][(l + 64) * 4] = ex;
        sv.x += ex.x; sv.y += ex.y; sv.z += ex.z; sv.w += ex.w;
    }
    for (int j = l + 128; j < deg; j += 64) {
        int s2 = srcsort[base + j];
        float4 a = asrc4[s2];
        sv.x += __expf(lrelu(a.x + ad.x) - mx.x);
        sv.y += __expf(lrelu(a.y + ad.y) - mx.y);
        sv.z += __expf(lrelu(a.z + ad.z) - mx.z);
        sv.w += __expf(lrelu(a.w + ad.w) - mx.w);
    }
    for (int m = 1; m < 64; m <<= 1) {
        sv.x += __shfl_xor(sv.x, m); sv.y += __shfl_xor(sv.y, m);
        sv.z += __shfl_xor(sv.z, m); sv.w += __shfl_xor(sv.w, m);
    }
    int hd = l >> 4;
    float mh  = hd == 0 ? mx.x : hd == 1 ? mx.y : hd == 2 ? mx.z : mx.w;
    float sh  = hd == 0 ? sv.x : hd == 1 ? sv.y : hd == 2 ? sv.z : sv.w;
    float adh = hd == 0 ? ad.x : hd == 1 ? ad.y : hd == 2 ? ad.z : ad.w;
    float inv = 1.f / fmaxf(sh, 1e-16f);
    float4 accv = make_float4(0.f, 0.f, 0.f, 0.f);
    const uint2* h2p = (const uint2*)hbf;
    int dcap = deg < 128 ? deg : 128;
#pragma unroll 2
    for (int j = 0; j < dcap; j++) {
        int src = s_src[w][j];
        float wgt = s_wf[w][j * 4 + hd] * inv;
        uint2 u = h2p[(size_t)src * 64 + l];
        accv.x += wgt * __uint_as_float(u.x << 16);
        accv.y += wgt * __uint_as_float(u.x & 0xffff0000u);
        accv.z += wgt * __uint_as_float(u.y << 16);
        accv.w += wgt * __uint_as_float(u.y & 0xffff0000u);
    }
    for (int j = 128; j < deg; j++) {
        int src = srcsort[base + j];
        float4 a = asrc4[src];
        float ah = hd == 0 ? a.x : hd == 1 ? a.y : hd == 2 ? a.z : a.w;
        float wgt = __expf(lrelu(ah + adh) - mh) * inv;
        uint2 u = h2p[(size_t)src * 64 + l];
        accv.x += wgt * __uint_as_float(u.x << 16);
        accv.y += wgt * __uint_as_float(u.x & 0xffff0000u);
        accv.z += wgt * __uint_as_float(u.y << 16);
        accv.w += wgt * __uint_as_float(u.y & 0xffff0000u);
    }
    ushort4 o;
    o.x = f2bf(accv.x + bgv.x); o.y = f2bf(accv.y + bgv.y);
    o.z = f2bf(accv.z + bgv.z); o.w = f2bf(accv.w + bgv.w);
    outbf[(size_t)dst * 64 + l] = o;
}

// ---------- 10. column stats of outp (bf16, multi-copy), 1024 blocks ----------
__global__ __launch_bounds__(256) void k_bn3_stats(
        const uint2* __restrict__ op2, float* __restrict__ bn3c) {
    __shared__ float4 ta[256];
    __shared__ float4 tb[256];
    int t = threadIdx.x;
    int cq = t & 63, rsub = t >> 6;
    float4 a = make_float4(0.f, 0.f, 0.f, 0.f);
    float4 b = make_float4(0.f, 0.f, 0.f, 0.f);
    for (int r = blockIdx.x * 4 + rsub; r < N_; r += gridDim.x * 4) {
        uint2 u = op2[(size_t)r * 64 + cq];
        float x0 = __uint_as_float(u.x << 16);
        float x1 = __uint_as_float(u.x & 0xffff0000u);
        float x2 = __uint_as_float(u.y << 16);
        float x3 = __uint_as_float(u.y & 0xffff0000u);
        a.x += x0; a.y += x1; a.z += x2; a.w += x3;
        b.x += x0 * x0; b.y += x1 * x1; b.z += x2 * x2; b.w += x3 * x3;
    }
    ta[t] = a; tb[t] = b;
    __syncthreads();
    if (t < 64) {
        float4 sa = ta[t], sb = tb[t];
#pragma unroll
        for (int r = 1; r < 4; r++) {
            float4 xa = ta[r * 64 + t], xb = tb[r * 64 + t];
            sa.x += xa.x; sa.y += xa.y; sa.z += xa.z; sa.w += xa.w;
            sb.x += xb.x; sb.y += xb.y; sb.z += xb.z; sb.w += xb.w;
        }
        float* dst = bn3c + (size_t)(blockIdx.x & (BN3C - 1)) * 512;
        int c = t << 2;
        atomicAdd(&dst[c + 0], sa.x); atomicAdd(&dst[c + 1], sa.y);
        atomicAdd(&dst[c + 2], sa.z); atomicAdd(&dst[c + 3], sa.w);
        atomicAdd(&dst[256 + c + 0], sb.x); atomicAdd(&dst[256 + c + 1], sb.y);
        atomicAdd(&dst[256 + c + 2], sb.z); atomicAdd(&dst[256 + c + 3], sb.w);
    }
}

// ---------- 11. graph mean-pool of elu(bn3(outp)) + final MLP ----------
__global__ __launch_bounds__(256) void k_pool_mlp(
        const uint2* __restrict__ op2, const int* __restrict__ batch,
        const float* __restrict__ bn3c,
        const float* __restrict__ bn3g, const float* __restrict__ bn3b,
        const float* __restrict__ W1, const float* __restrict__ b1,
        const float* __restrict__ W2, const float* __restrict__ b2,
        float* __restrict__ out) {
    __shared__ float4 tile[256];
    __shared__ float  pl[256];
    __shared__ float  hm[64];
    __shared__ float  s3[256];
    __shared__ float  q3[256];
    int g = blockIdx.x;
    int t = threadIdx.x;
    int cq = t & 63, rsub = t >> 6;
    int c4 = cq << 2;
    {
        float s = 0.f, q = 0.f;
        for (int c = 0; c < BN3C; c++) {
            s += bn3c[c * 512 + t];
            q += bn3c[c * 512 + 256 + t];
        }
        s3[t] = s; q3[t] = q;
    }
    int lo = 0, hi = N_;
    while (lo < hi) { int mid = (lo + hi) >> 1; if (batch[mid] < g) lo = mid + 1; else hi = mid; }
    int start = lo;
    hi = N_;
    while (lo < hi) { int mid = (lo + hi) >> 1; if (batch[mid] < g + 1) lo = mid + 1; else hi = mid; }
    int end = lo;
    __syncthreads();
    float scv[4], shv[4];
#pragma unroll
    for (int k = 0; k < 4; k++) {
        int c = c4 + k;
        float mu  = s3[c] / (float)N_;
        float var = q3[c] / (float)N_ - mu * mu;
        float s   = bn3g[c] * rsqrtf(var + EPS_);
        scv[k] = s; shv[k] = bn3b[c] - mu * s;
    }
    float4 acc = make_float4(0.f, 0.f, 0.f, 0.f);
    for (int n = start + rsub; n < end; n += 4) {
        uint2 u = op2[(size_t)n * 64 + cq];
        float e0 = __uint_as_float(u.x << 16)          * scv[0] + shv[0];
        float e1 = __uint_as_float(u.x & 0xffff0000u)  * scv[1] + shv[1];
        float e2 = __uint_as_float(u.y << 16)          * scv[2] + shv[2];
        float e3 = __uint_as_float(u.y & 0xffff0000u)  * scv[3] + shv[3];
        acc.x += (e0 > 0.f) ? e0 : expm1f(e0);
        acc.y += (e1 > 0.f) ? e1 : expm1f(e1);
        acc.z += (e2 > 0.f) ? e2 : expm1f(e2);
        acc.w += (e3 > 0.f) ? e3 : expm1f(e3);
    }
    tile[t] = acc;
    __syncthreads();
    if (t < 64) {
        float4 s = tile[t];
#pragma unroll
        for (int r = 1; r < 4; r++) {
            float4 xv = tile[r * 64 + t];
            s.x += xv.x; s.y += xv.y; s.z += xv.z; s.w += xv.w;
        }
        float icn = 1.f / fmaxf((float)(end - start), 1.f);
        ((float4*)pl)[t] = make_float4(s.x * icn, s.y * icn, s.z * icn, s.w * icn);
    }
    __syncthreads();
    {
        int j = t >> 2, part = t & 3;
        const float* w1r = W1 + j * 256 + part * 64;
        const float* plr = pl + part * 64;
        float a = 0.f;
#pragma unroll
        for (int c = 0; c < 64; c++) a += w1r[c] * plr[c];
        a += __shfl_xor(a, 1);
        a += __shfl_xor(a, 2);
        if (part == 0) hm[j] = fmaxf(a + b1[j], 0.f);
    }
    __syncthreads();
    if (t < 128) {
        int j = t >> 6, k = t & 63;
        float p = W2[j * 64 + k] * hm[k];
        for (int m = 1; m < 64; m <<= 1) p += __shfl_xor(p, m);
        if (k == 0) out[g * 2 + j] = p + b2[j];
    }
}

extern "C" void kernel_launch(void* const* d_in, const int* in_sizes, int n_in,
                              void* d_out, int out_size, void* d_ws, size_t ws_size,
                              hipStream_t stream) {
    const float* x    = (const float*)d_in[0];
    const int*   ei   = (const int*)d_in[1];
    const int*   batch= (const int*)d_in[2];
    const float* lng  = (const float*)d_in[3];
    const float* lnb  = (const float*)d_in[4];
    const float* bn1g = (const float*)d_in[5];
    const float* bn1b = (const float*)d_in[6];
    const float* Wc   = (const float*)d_in[7];
    const float* bc   = (const float*)d_in[8];
    const float* bn2g = (const float*)d_in[9];
    const float* bn2b = (const float*)d_in[10];
    const float* Wp   = (const float*)d_in[11];
    const float* bp   = (const float*)d_in[12];
    const float* Wg   = (const float*)d_in[13];
    const float* atts = (const float*)d_in[14];
    const float* attd = (const float*)d_in[15];
    const float* bg   = (const float*)d_in[16];
    const float* bn3g = (const float*)d_in[17];
    const float* bn3b = (const float*)d_in[18];
    const float* W1   = (const float*)d_in[19];
    const float* b1   = (const float*)d_in[20];
    const float* W2   = (const float*)d_in[21];
    const float* b2   = (const float*)d_in[22];
    float* out = (float*)d_out;

    char* w8 = (char*)d_ws;
    float* bn1c   = (float*)(w8 + OFF_BN1C);
    float* bn2c   = (float*)(w8 + OFF_BN2C);
    float* bn3c   = (float*)(w8 + OFF_BN3C);
    int*   count  = (int*)(w8 + OFF_COUNT);
    int*   offs   = (int*)(w8 + OFF_OFFS);
    int*   bh     = (int*)(w8 + OFF_BH);
    int*   btot   = (int*)(w8 + OFF_BTOT);
    int*   bbase  = (int*)(w8 + OFF_BBASE);
    unsigned short* sortd = (unsigned short*)(w8 + OFF_SORTD);
    int*   sorts  = (int*)(w8 + OFF_SORTS);
    int*   srcs   = (int*)(w8 + OFF_SRCS);
    float* Wc2t   = (float*)(w8 + OFF_WC2);
    float* c2     = (float*)(w8 + OFF_C2);
    float* Wp2    = (float*)(w8 + OFF_WP2);
    float* cp     = (float*)(w8 + OFF_CP);
    float* Wgt    = (float*)(w8 + OFF_WGT);
    float* asrc   = (float*)(w8 + OFF_ASRC);
    float* adst   = (float*)(w8 + OFF_ADST);
    float* z      = (float*)(w8 + OFF_Z);
    ushort4* hbf  = (ushort4*)(w8 + OFF_H);
    ushort4* outp = (ushort4*)(w8 + OFF_OUTP);

    hipMemsetAsync(d_ws, 0, ZERO_BYTES, stream);

    k_bn1<<<2048, 256, 0, stream>>>(x, bn1c);
    k_rhist<<<NBLK, 256, 0, stream>>>(ei, bh);
    k_fold1<<<1, 512, 0, stream>>>(bn1c, bn1g, bn1b, Wc, bc, Wc2t, c2);
    k_rscan<<<256, 256, 0, stream>>>(bh, btot);
    k_z<<<(N_ + 127) / 128, 512, 0, stream>>>(x, Wc2t, c2, lng, lnb, z, bn2c);
    k_rbase<<<1, 256, 0, stream>>>(btot, bbase);
    k_rscatter<<<NBLK, 256, 0, stream>>>(ei, bh, bbase, sortd, sorts);
    k_fold2_wgt<<<65, 256, 0, stream>>>(bn2c, bn2g, bn2b, Wp, bp, Wp2, cp, Wg, Wgt);
    k_rsort2<<<196, 256, 0, stream>>>(sortd, sorts, bbase, count, offs, srcs);
    k_h2<<<(N_ + 127) / 128, 512, 0, stream>>>(z, Wp2, cp, Wgt, atts, attd, hbf, asrc, adst);
    k_agg<<<N_ / 4, 256, 0, stream>>>(count, offs, srcs, asrc, adst, hbf, bg, outp);
    k_bn3_stats<<<1024, 256, 0, stream>>>((const uint2*)outp, bn3c);
    k_pool_mlp<<<G_, 256, 0, stream>>>((const uint2*)outp, batch, bn3c,
                                       bn3g, bn3b, W1, b1, W2, b2, out);
}